// Round 12
// baseline (1298.295 us; speedup 1.0000x reference)
//
#include <hip/hip_runtime.h>
#include <stdint.h>

#define B_  32768
#define Q_  1024
#define E_  1024
#define CAPF  16384   // stage-1 flag capacity (rows refined by bf16 3-pass)
#define CAPF2 1024    // stage-2 flag capacity (rows refined by fp64)

typedef __attribute__((ext_vector_type(8))) short bf16x8;
typedef __attribute__((ext_vector_type(8))) _Float16 f16x8;
typedef __attribute__((ext_vector_type(8))) unsigned short u16x8;
typedef __attribute__((ext_vector_type(4))) float f32x4;
typedef unsigned short us;

__device__ __forceinline__ f32x4 MFMA16(bf16x8 a, bf16x8 b, f32x4 c) {
    return __builtin_amdgcn_mfma_f32_16x16x32_bf16(a, b, c, 0, 0, 0);
}
__device__ __forceinline__ f32x4 MFMA16H(bf16x8 a, bf16x8 b, f32x4 c) {
    return __builtin_amdgcn_mfma_f32_16x16x32_f16(
        __builtin_bit_cast(f16x8, a), __builtin_bit_cast(f16x8, b), c, 0, 0, 0);
}

__device__ __forceinline__ us f2bf(float v) {   // RNE fp32->bf16
    unsigned u = __float_as_uint(v);
    u += 0x7FFFu + ((u >> 16) & 1u);
    return (us)(u >> 16);
}
__device__ __forceinline__ float bf2f(us b) {
    return __uint_as_float(((unsigned)b) << 16);
}
__device__ __forceinline__ us f2h(float v) {    // RNE fp32->fp16 bits
    _Float16 h = (_Float16)v;
    return __builtin_bit_cast(unsigned short, h);
}

// ---------------- plane prep kernels (memory-bound, run once) ---------------
__global__ __launch_bounds__(256)
void split_planes_k(const float* __restrict__ in, us* __restrict__ hi,
                    us* __restrict__ lo, int n8) {
    int i = blockIdx.x * 256 + threadIdx.x;
    const int stride = gridDim.x * 256;
    for (; i < n8; i += stride) {
        float4 a = ((const float4*)in)[i * 2];
        float4 b = ((const float4*)in)[i * 2 + 1];
        float f[8] = {a.x, a.y, a.z, a.w, b.x, b.y, b.z, b.w};
        u16x8 h, l;
#pragma unroll
        for (int j = 0; j < 8; ++j) {
            us c0 = f2bf(f[j]);
            h[j] = c0;
            l[j] = f2bf(f[j] - bf2f(c0));   // exact residual (Sterbenz)
        }
        ((u16x8*)hi)[i] = h;
        ((u16x8*)lo)[i] = l;
    }
}

__global__ __launch_bounds__(256)
void cvt_plane_k(const float* __restrict__ in, us* __restrict__ hi, int n8) {
    int i = blockIdx.x * 256 + threadIdx.x;
    const int stride = gridDim.x * 256;
    for (; i < n8; i += stride) {
        float4 a = ((const float4*)in)[i * 2];
        float4 b = ((const float4*)in)[i * 2 + 1];
        float f[8] = {a.x, a.y, a.z, a.w, b.x, b.y, b.z, b.w};
        u16x8 h;
#pragma unroll
        for (int j = 0; j < 8; ++j) h[j] = f2bf(f[j]);
        ((u16x8*)hi)[i] = h;
    }
}

__global__ __launch_bounds__(256)
void cvt_plane_h(const float* __restrict__ in, us* __restrict__ hi, int n8) {
    int i = blockIdx.x * 256 + threadIdx.x;
    const int stride = gridDim.x * 256;
    for (; i < n8; i += stride) {
        float4 a = ((const float4*)in)[i * 2];
        float4 b = ((const float4*)in)[i * 2 + 1];
        float f[8] = {a.x, a.y, a.z, a.w, b.x, b.y, b.z, b.w};
        u16x8 h;
#pragma unroll
        for (int j = 0; j < 8; ++j) h[j] = f2h(f[j]);
        ((u16x8*)hi)[i] = h;
    }
}

// gather flagged rows of fp32 x and split into bf16 hi/lo planes [CAPF][Q]
__global__ __launch_bounds__(256)
void gather_split(const float* __restrict__ X, const int* __restrict__ flags,
                  const int* __restrict__ cnt, us* __restrict__ G0,
                  us* __restrict__ G1) {
    const int n = min(*cnt, CAPF);
    for (int it = blockIdx.x; it < n; it += gridDim.x) {
        int row = flags[it];
        if ((unsigned)row >= B_) row = 0;            // replay-safety clamp
        float4 v = ((const float4*)(X + (size_t)row * Q_))[threadIdx.x];
        float f[4] = {v.x, v.y, v.z, v.w};
        us h[4], l[4];
#pragma unroll
        for (int j = 0; j < 4; ++j) {
            h[j] = f2bf(f[j]);
            l[j] = f2bf(f[j] - bf2f(h[j]));
        }
        *(uint2*)&G0[(size_t)it * Q_ + threadIdx.x * 4] = *(uint2*)h;
        *(uint2*)&G1[(size_t)it * Q_ + threadIdx.x * 4] = *(uint2*)l;
    }
}

// ============================================================================
// 256x256-tile GEMM (round-8 verified core). 8 waves (2Mx4N), BK=32, 4-slot
// whole-tile LDS ring (128 KiB), safe deep pipeline:
//   half-step: RD(frags t+1) || stage(t+4, clamped) || MFMA(t)
//              -> lgkmcnt(0) -> vmcnt(8) -> s_barrier
// NSEG=3: acc = A0B0 + A0B1 + A1B0 over K'=3K (fp32-grade split-bf16).
// EMIT: 0=fp32, 1=bf16 hi/lo pair, 2=fp16. FP16: f16 MFMA.
// ============================================================================
#define LGKM0() asm volatile("s_waitcnt lgkmcnt(0)" ::: "memory")
#define VMC8()  asm volatile("s_waitcnt vmcnt(8)" ::: "memory")
#define BAR()   __builtin_amdgcn_s_barrier()
#define RD_AB(Aarr, Barr, slot) { \
    const us* _la = &LA[(slot) * 8192]; const us* _lb = &LB[(slot) * 8192]; \
    _Pragma("unroll") for (int mf = 0; mf < 8; ++mf) Aarr[mf] = *(const bf16x8*)&_la[ago[mf]]; \
    _Pragma("unroll") for (int nf = 0; nf < 4; ++nf) Barr[nf] = *(const bf16x8*)&_lb[bgo[nf]]; }
#define CLX(AF, BF) { __builtin_amdgcn_s_setprio(1); \
    _Pragma("unroll") for (int mf = 0; mf < 8; ++mf) { \
        _Pragma("unroll") for (int nf = 0; nf < 4; ++nf) { \
            if constexpr (FP16) acc[mf][nf] = MFMA16H(AF[mf], BF[nf], acc[mf][nf]); \
            else               acc[mf][nf] = MFMA16 (AF[mf], BF[nf], acc[mf][nf]); } } \
    __builtin_amdgcn_s_setprio(0); }

template<int NSEG, int K, int EMIT, bool RELU, bool FP16>
__global__ __launch_bounds__(512, 2)
void gemm4r(const us* __restrict__ A0p, const us* __restrict__ A1p,
            const us* __restrict__ B0p, const us* __restrict__ B1p,
            void* __restrict__ Cp0, void* __restrict__ Cp1, int N) {
    constexpr int TPS = K / 32;
    constexpr int NT  = NSEG * TPS;
    static_assert(NT % 2 == 0 && NT >= 4, "shape");
    __shared__ __align__(16) us LA[4 * 8192];
    __shared__ __align__(16) us LB[4 * 8192];

    const int t = threadIdx.x;
    const int wv = t >> 6, lane = t & 63;
    const int lanelo = lane & 15, kq = lane >> 4;
    const int wm = wv >> 2, wn = wv & 3;

    const int q8 = gridDim.x >> 3;       // grid % 8 == 0 (T1 bijective swizzle)
    const int logical = ((int)blockIdx.x & 7) * q8 + ((int)blockIdx.x >> 3);
    const int gx = N >> 8;
    const int m0 = (logical / gx) * 256, n0 = (logical % gx) * 256;

    int soff[2], ldst[2];
#pragma unroll
    for (int i = 0; i < 2; ++i) {
        int s = i * 512 + t;
        int row = s >> 2, c = s & 3;
        soff[i] = row * K + (c ^ ((row >> 1) & 3)) * 8;
        ldst[i] = (i * 512 + wv * 64) * 8;
    }
    int ago[8], bgo[4];
#pragma unroll
    for (int mf = 0; mf < 8; ++mf) {
        int row = wm * 128 + mf * 16 + lanelo;
        ago[mf] = (row * 4 + (kq ^ ((row >> 1) & 3))) * 8;
    }
#pragma unroll
    for (int nf = 0; nf < 4; ++nf) {
        int row = wn * 64 + nf * 16 + lanelo;
        bgo[nf] = (row * 4 + (kq ^ ((row >> 1) & 3))) * 8;
    }

    auto stage = [&](int tv) {
        int slot = tv & 3;
        int seg = tv / TPS;
        int kb  = (tv - seg * TPS) * 32;
        const us* Ap = (NSEG == 1 || seg < 2) ? A0p : A1p;
        const us* Bp = (NSEG == 3 && seg == 1) ? B1p : B0p;
        const us* Abase = Ap + (size_t)m0 * K + kb;
        const us* Bbase = Bp + (size_t)n0 * K + kb;
        us* dA = &LA[slot * 8192];
        us* dB = &LB[slot * 8192];
#pragma unroll
        for (int i = 0; i < 2; ++i) {
            __builtin_amdgcn_global_load_lds(
                (const __attribute__((address_space(1))) void*)(Abase + soff[i]),
                (__attribute__((address_space(3))) void*)(dA + ldst[i]), 16, 0, 0);
            __builtin_amdgcn_global_load_lds(
                (const __attribute__((address_space(1))) void*)(Bbase + soff[i]),
                (__attribute__((address_space(3))) void*)(dB + ldst[i]), 16, 0, 0);
        }
    };

    f32x4 acc[8][4];
#pragma unroll
    for (int i = 0; i < 8; ++i)
#pragma unroll
        for (int j = 0; j < 4; ++j) acc[i][j] = (f32x4){0.f, 0.f, 0.f, 0.f};

    bf16x8 aE[8], bE[4], aO[8], bO[4];

    stage(0); stage(1); stage(2);
    VMC8();  BAR();
    RD_AB(aE, bE, 0);
    stage(3);
    LGKM0(); VMC8(); BAR();

    for (int tt = 0; tt < NT; tt += 2) {
        RD_AB(aO, bO, (tt + 1) & 3);
        { int tv = tt + 4; if (tv > NT - 1) tv = NT - 1; stage(tv); }
        CLX(aE, bE);
        LGKM0(); VMC8(); BAR();
        { int tn = (tt + 2 < NT) ? (tt + 2) : (NT - 1);
          RD_AB(aE, bE, tn & 3); }
        { int tv = tt + 5; if (tv > NT - 1) tv = NT - 1; stage(tv); }
        CLX(aO, bO);
        LGKM0(); VMC8(); BAR();
    }

    // epilogue: C/D layout col=lane&15, row=(lane>>4)*4+reg (m89/m91)
#pragma unroll
    for (int mf = 0; mf < 8; ++mf)
#pragma unroll
        for (int nf = 0; nf < 4; ++nf)
#pragma unroll
            for (int r = 0; r < 4; ++r) {
                int row = m0 + wm * 128 + mf * 16 + kq * 4 + r;
                int col = n0 + wn * 64 + nf * 16 + lanelo;
                float v = acc[mf][nf][r];
                if constexpr (RELU) v = fmaxf(v, 0.f);
                if constexpr (EMIT == 1) {
                    us c0 = f2bf(v);
                    ((us*)Cp0)[(size_t)row * N + col] = c0;
                    ((us*)Cp1)[(size_t)row * N + col] = f2bf(v - bf2f(c0));
                } else if constexpr (EMIT == 2) {
                    ((us*)Cp0)[(size_t)row * N + col] = f2h(v);
                } else {
                    ((float*)Cp0)[(size_t)row * N + col] = v;
                }
            }
}

// ============================================================================
// 128x128-tile all-plane GEMM (round-5 verified core) for the gathered pass:
// 4 waves, 32 KiB LDS, 4 blocks/CU -> high occupancy for small-M work.
// DYN: early-exit m-tiles beyond ceil(n/128) (n = *ncnt flagged rows).
// ============================================================================
template<int NPASS, bool RELU, bool EMITP, bool DYN>
__global__ __launch_bounds__(256, 4)
void gemm_pp(const us* __restrict__ A0, const us* __restrict__ A1,
             const us* __restrict__ B0, const us* __restrict__ B1,
             void* __restrict__ Cp0, void* __restrict__ Cp1,
             int N, int K, const int* __restrict__ ncnt) {
    __shared__ __align__(16) us A0s[128 * 32];
    __shared__ __align__(16) us B0s[128 * 32];
    __shared__ __align__(16) us A1s[(NPASS == 3) ? 128 * 32 : 8];
    __shared__ __align__(16) us B1s[(NPASS == 3) ? 128 * 32 : 8];

    const int t = threadIdx.x;
    const int wave = t >> 6, lane = t & 63;
    const int lanelo = lane & 15, kq = lane >> 4;
    const int wm = wave >> 1, wn = wave & 1;
    const int q8 = gridDim.x >> 3;                 // grid divisible by 8
    const int logical = ((int)blockIdx.x & 7) * q8 + ((int)blockIdx.x >> 3);
    const int gx = N >> 7;
    const int m0 = (logical / gx) * 128, n0 = (logical % gx) * 128;

    if constexpr (DYN) {
        int nn = *ncnt; if (nn > CAPF) nn = CAPF;
        if (m0 >= ((nn + 127) & ~127)) return;
    }

    f32x4 acc[4][4];
#pragma unroll
    for (int i = 0; i < 4; ++i)
#pragma unroll
        for (int j = 0; j < 4; ++j) acc[i][j] = (f32x4){0.f, 0.f, 0.f, 0.f};

    for (int kt = 0; kt < K; kt += 32) {
        __syncthreads();
#pragma unroll
        for (int g = 0; g < 2; ++g) {
            int c = (g * 4 + wave) * 64 + lane;
            int row = c >> 2;
            int koff = (c & 3) ^ (row & 3);        // pre-swizzled source
            size_t offa = (size_t)(m0 + row) * K + kt + koff * 8;
            size_t offb = (size_t)(n0 + row) * K + kt + koff * 8;
            int dst = (g * 4 + wave) * 512;
            __builtin_amdgcn_global_load_lds(
                (const __attribute__((address_space(1))) void*)(A0 + offa),
                (__attribute__((address_space(3))) void*)&A0s[dst], 16, 0, 0);
            __builtin_amdgcn_global_load_lds(
                (const __attribute__((address_space(1))) void*)(B0 + offb),
                (__attribute__((address_space(3))) void*)&B0s[dst], 16, 0, 0);
            if constexpr (NPASS == 3) {
                __builtin_amdgcn_global_load_lds(
                    (const __attribute__((address_space(1))) void*)(A1 + offa),
                    (__attribute__((address_space(3))) void*)&A1s[dst], 16, 0, 0);
                __builtin_amdgcn_global_load_lds(
                    (const __attribute__((address_space(1))) void*)(B1 + offb),
                    (__attribute__((address_space(3))) void*)&B1s[dst], 16, 0, 0);
            }
        }
        __syncthreads();

        bf16x8 a0[4], a1[4];
#pragma unroll
        for (int mf = 0; mf < 4; ++mf) {
            int ar = wm * 64 + mf * 16 + lanelo;
            int ac = ar * 4 + (kq ^ (ar & 3));
            a0[mf] = *(const bf16x8*)&A0s[ac * 8];
            if constexpr (NPASS == 3) a1[mf] = *(const bf16x8*)&A1s[ac * 8];
        }
#pragma unroll
        for (int nf = 0; nf < 4; ++nf) {
            int br = wn * 64 + nf * 16 + lanelo;
            int bc = br * 4 + (kq ^ (br & 3));
            bf16x8 vb0 = *(const bf16x8*)&B0s[bc * 8];
#pragma unroll
            for (int mf = 0; mf < 4; ++mf) acc[mf][nf] = MFMA16(a0[mf], vb0, acc[mf][nf]);
            if constexpr (NPASS == 3) {
                bf16x8 vb1 = *(const bf16x8*)&B1s[bc * 8];
#pragma unroll
                for (int mf = 0; mf < 4; ++mf) acc[mf][nf] = MFMA16(a0[mf], vb1, acc[mf][nf]);
#pragma unroll
                for (int mf = 0; mf < 4; ++mf) acc[mf][nf] = MFMA16(a1[mf], vb0, acc[mf][nf]);
            }
        }
    }

#pragma unroll
    for (int mf = 0; mf < 4; ++mf)
#pragma unroll
        for (int nf = 0; nf < 4; ++nf)
#pragma unroll
            for (int r = 0; r < 4; ++r) {
                int row = m0 + wm * 64 + mf * 16 + kq * 4 + r;
                int col = n0 + wn * 64 + nf * 16 + lanelo;
                float v = acc[mf][nf][r];
                if constexpr (RELU) v = fmaxf(v, 0.f);
                if constexpr (EMITP) {
                    us c0 = f2bf(v);
                    ((us*)Cp0)[(size_t)row * N + col] = c0;
                    ((us*)Cp1)[(size_t)row * N + col] = f2bf(v - bf2f(c0));
                } else {
                    ((float*)Cp0)[(size_t)row * N + col] = v;
                }
            }
}

// ---------------- fallback GEMM (round-4 path, in-kernel split) -------------
__device__ __forceinline__ int chunk_of(int row, int koff) {
    return row * 4 + (koff ^ (row & 3));
}

template<int NPASS>
__device__ __forceinline__ void split_store(us* S0, us* S1,
                                            int rowX, int koffX, float4 a, float4 b) {
    int ch = chunk_of(rowX, koffX);
    float f[8] = {a.x, a.y, a.z, a.w, b.x, b.y, b.z, b.w};
    bf16x8 lo, hi;
#pragma unroll
    for (int j = 0; j < 8; ++j) {
        us c0 = f2bf(f[j]);
        lo[j] = (short)c0;
        hi[j] = (short)f2bf(f[j] - bf2f(c0));
    }
    *(bf16x8*)&S0[ch * 8] = lo;
    if constexpr (NPASS == 3) *(bf16x8*)&S1[ch * 8] = hi;
}

template<int NPASS, bool AF32, bool RELU, bool EMITP>
__global__ __launch_bounds__(256, 2)
void gemm3p(const void* __restrict__ Ap0, const void* __restrict__ Ap1,
            const float* __restrict__ Wf,
            void* __restrict__ Cp0, void* __restrict__ Cp1,
            int M, int N, int K) {
    __shared__ __align__(16) us A0s[128 * 32];
    __shared__ __align__(16) us B0s[128 * 32];
    __shared__ __align__(16) us A1s[(NPASS == 3) ? 128 * 32 : 8];
    __shared__ __align__(16) us B1s[(NPASS == 3) ? 128 * 32 : 8];

    const int t = threadIdx.x;
    const int wave = t >> 6, lane = t & 63;
    const int lanelo = lane & 15, kq = lane >> 4;
    const int wm = wave >> 1, wn = wave & 1;
    const int m0 = blockIdx.y * 128, n0 = blockIdx.x * 128;
    const int brow = t >> 1, bhalf = t & 1;

    f32x4 acc[4][4];
#pragma unroll
    for (int i = 0; i < 4; ++i)
#pragma unroll
        for (int j = 0; j < 4; ++j) acc[i][j] = (f32x4){0.f, 0.f, 0.f, 0.f};

    for (int kt = 0; kt < K; kt += 32) {
        __syncthreads();
        const float* wp = Wf + (size_t)(n0 + brow) * K + kt + bhalf * 16;
        float4 v0 = *(const float4*)(wp + 0);
        float4 v1 = *(const float4*)(wp + 4);
        float4 v2 = *(const float4*)(wp + 8);
        float4 v3 = *(const float4*)(wp + 12);
        if constexpr (AF32) {
            const float* ap = (const float*)Ap0 + (size_t)(m0 + brow) * K + kt + bhalf * 16;
            float4 u0 = *(const float4*)(ap + 0);
            float4 u1 = *(const float4*)(ap + 4);
            float4 u2 = *(const float4*)(ap + 8);
            float4 u3 = *(const float4*)(ap + 12);
            split_store<NPASS>(A0s, A1s, brow, bhalf * 2 + 0, u0, u1);
            split_store<NPASS>(A0s, A1s, brow, bhalf * 2 + 1, u2, u3);
        } else {
#pragma unroll
            for (int g = 0; g < 2; ++g) {
                int c = (g * 4 + wave) * 64 + lane;
                int row = c >> 2;
                int koff = (c & 3) ^ (row & 3);
                const us* s0 = (const us*)Ap0 + (size_t)(m0 + row) * K + kt + koff * 8;
                __builtin_amdgcn_global_load_lds(
                    (const __attribute__((address_space(1))) void*)s0,
                    (__attribute__((address_space(3))) void*)&A0s[(size_t)(g * 4 + wave) * 512],
                    16, 0, 0);
                if constexpr (NPASS == 3) {
                    const us* s1 = (const us*)Ap1 + (size_t)(m0 + row) * K + kt + koff * 8;
                    __builtin_amdgcn_global_load_lds(
                        (const __attribute__((address_space(1))) void*)s1,
                        (__attribute__((address_space(3))) void*)&A1s[(size_t)(g * 4 + wave) * 512],
                        16, 0, 0);
                }
            }
        }
        split_store<NPASS>(B0s, B1s, brow, bhalf * 2 + 0, v0, v1);
        split_store<NPASS>(B0s, B1s, brow, bhalf * 2 + 1, v2, v3);
        __syncthreads();

        bf16x8 a0[4], a1[4];
#pragma unroll
        for (int mf = 0; mf < 4; ++mf) {
            int ar = wm * 64 + mf * 16 + lanelo;
            int ac = chunk_of(ar, kq);
            a0[mf] = *(const bf16x8*)&A0s[ac * 8];
            if constexpr (NPASS == 3) a1[mf] = *(const bf16x8*)&A1s[ac * 8];
        }
#pragma unroll
        for (int nf = 0; nf < 4; ++nf) {
            int br = wn * 64 + nf * 16 + lanelo;
            int bc = chunk_of(br, kq);
            bf16x8 vb0 = *(const bf16x8*)&B0s[bc * 8];
#pragma unroll
            for (int mf = 0; mf < 4; ++mf) acc[mf][nf] = MFMA16(a0[mf], vb0, acc[mf][nf]);
            if constexpr (NPASS == 3) {
                bf16x8 vb1 = *(const bf16x8*)&B1s[bc * 8];
#pragma unroll
                for (int mf = 0; mf < 4; ++mf) acc[mf][nf] = MFMA16(a0[mf], vb1, acc[mf][nf]);
#pragma unroll
                for (int mf = 0; mf < 4; ++mf) acc[mf][nf] = MFMA16(a1[mf], vb0, acc[mf][nf]);
            }
        }
    }

#pragma unroll
    for (int mf = 0; mf < 4; ++mf)
#pragma unroll
        for (int nf = 0; nf < 4; ++nf)
#pragma unroll
            for (int r = 0; r < 4; ++r) {
                int row = m0 + wm * 64 + mf * 16 + kq * 4 + r;
                int col = n0 + wn * 64 + nf * 16 + lanelo;
                float v = acc[mf][nf][r];
                if constexpr (RELU) v = fmaxf(v, 0.f);
                if constexpr (EMITP) {
                    us c0 = f2bf(v);
                    ((us*)Cp0)[(size_t)row * N + col] = c0;
                    ((us*)Cp1)[(size_t)row * N + col] = f2bf(v - bf2f(c0));
                } else {
                    ((float*)Cp0)[(size_t)row * N + col] = v;
                }
            }
}

// k[row] = argmax+1 (first occurrence); flag rows whose top-2 gap < theta
__global__ __launch_bounds__(256)
void row_argmax_flag(const float* __restrict__ S, int* __restrict__ KV,
                     int* __restrict__ flags, int* __restrict__ cnt, float theta) {
    int row = blockIdx.x * 4 + (threadIdx.x >> 6);
    int lane = threadIdx.x & 63;
    const float* s = S + (size_t)row * Q_;
    float b1 = -3.4e38f, b2 = -3.4e38f; int i1 = 0;
    for (int j = lane; j < Q_; j += 64) {
        float v = s[j];
        if (v > b1) { b2 = b1; b1 = v; i1 = j; }
        else if (v > b2) b2 = v;
    }
#pragma unroll
    for (int m = 1; m < 64; m <<= 1) {
        float o1 = __shfl_xor(b1, m);
        int   oi = __shfl_xor(i1, m);
        float o2 = __shfl_xor(b2, m);
        if (o1 > b1 || (o1 == b1 && oi < i1)) {
            b2 = fmaxf(b1, o2);
            b1 = o1; i1 = oi;
        } else {
            b2 = fmaxf(b2, o1);
        }
    }
    if (lane == 0) {
        KV[row] = i1 + 1;
        if (b1 - b2 < theta) {
            int p = atomicAdd(cnt, 1);
            if (p < CAPF) flags[p] = row;
        }
    }
}

// argmax over gathered (pass-2) scores: scatter k, flag near-ties for fp64
__global__ __launch_bounds__(256)
void g_argmax_flag2(const float* __restrict__ SCg, const int* __restrict__ flags,
                    const int* __restrict__ cnt, int* __restrict__ KV,
                    int* __restrict__ flags2, int* __restrict__ cnt2) {
    const int lane = threadIdx.x & 63, wv = threadIdx.x >> 6;
    const int n = min(*cnt, CAPF);
    for (int it = blockIdx.x * 4 + wv; it < n; it += gridDim.x * 4) {
        const float* s = SCg + (size_t)it * Q_;
        float b1 = -3.4e38f, b2 = -3.4e38f; int i1 = 0;
        for (int j = lane; j < Q_; j += 64) {
            float v = s[j];
            if (v > b1) { b2 = b1; b1 = v; i1 = j; }
            else if (v > b2) b2 = v;
        }
#pragma unroll
        for (int m = 1; m < 64; m <<= 1) {
            float o1 = __shfl_xor(b1, m);
            int   oi = __shfl_xor(i1, m);
            float o2 = __shfl_xor(b2, m);
            if (o1 > b1 || (o1 == b1 && oi < i1)) {
                b2 = fmaxf(b1, o2);
                b1 = o1; i1 = oi;
            } else {
                b2 = fmaxf(b2, o1);
            }
        }
        if (lane == 0) {
            int r = flags[it];
            if ((unsigned)r < B_) {
                KV[r] = i1 + 1;
                if (b1 - b2 < 1e-3f) {
                    int p = atomicAdd(cnt2, 1);
                    if (p < CAPF2) flags2[p] = r;
                }
            }
        }
    }
}

// ---- parallel coalesced rescore (fp64): K compile-time -> fully unrolled,
// float4 vector loads so all weight loads batch-issue ----
template<int K, bool IN_BY_FLAG, bool RELU>
__global__ __launch_bounds__(256)
void rescore_gemm(const float* __restrict__ IN, const float* __restrict__ W,
                  float* __restrict__ OUT, const int* __restrict__ flags,
                  const int* __restrict__ cnt, int N, int cap) {
    __shared__ float xr[K];
    const int t = threadIdx.x, lane = t & 63, wv = t >> 6;
    const int n = min(*cnt, cap);
    const int chunks = N >> 4;
    for (int w = blockIdx.x; w < n * chunks; w += gridDim.x) {
        const int it = w / chunks, ch = w - it * chunks;
        int srow = IN_BY_FLAG ? flags[it] : it;
        if (IN_BY_FLAG && (unsigned)srow >= B_) srow = 0;   // replay-safety clamp
        const float* rp = IN + (size_t)srow * K;
        __syncthreads();
#pragma unroll
        for (int p = t; p < K / 4; p += 256)
            ((float4*)xr)[p] = ((const float4*)rp)[p];
        __syncthreads();
#pragma unroll
        for (int jj = 0; jj < 4; ++jj) {
            const int col = ch * 16 + wv * 4 + jj;
            const float* wr = W + (size_t)col * K;
            double a0 = 0.0, a1 = 0.0;
#pragma unroll
            for (int i = 0; i < K / 256; ++i) {
                const int k = i * 256 + lane * 4;
                float4 w4 = *(const float4*)(wr + k);
                float4 x4 = *(const float4*)(xr + k);
                a0 += (double)x4.x * w4.x + (double)x4.y * w4.y;
                a1 += (double)x4.z * w4.z + (double)x4.w * w4.w;
            }
            double a = a0 + a1;
#pragma unroll
            for (int m = 1; m < 64; m <<= 1) a += __shfl_xor(a, m);
            if (lane == 0) {
                float v = (float)a;
                if (RELU) v = fmaxf(v, 0.f);
                OUT[(size_t)it * N + col] = v;
            }
        }
    }
}

// final exact argmax over fp64-rescored rows, first-occurrence tie-break
__global__ __launch_bounds__(256)
void rescore_argmax(const float* __restrict__ SCF, const int* __restrict__ flags,
                    const int* __restrict__ cnt, int* __restrict__ KV, int cap) {
    const int lane = threadIdx.x & 63, wv = threadIdx.x >> 6;
    const int n = min(*cnt, cap);
    for (int it = blockIdx.x * 4 + wv; it < n; it += gridDim.x * 4) {
        const float* s = SCF + (size_t)it * Q_;
        float best = -3.4e38f; int bi = 0;
        for (int j = lane; j < Q_; j += 64) {
            float v = s[j];
            if (v > best) { best = v; bi = j; }
        }
#pragma unroll
        for (int m = 1; m < 64; m <<= 1) {
            float ov = __shfl_xor(best, m); int oi = __shfl_xor(bi, m);
            if (ov > best || (ov == best && oi < bi)) { best = ov; bi = oi; }
        }
        if (lane == 0) {
            int r = flags[it];
            if ((unsigned)r < B_) KV[r] = bi + 1;
        }
    }
}

// ---- stable top-k mask via in-register bit-descent radix select ----
__global__ __launch_bounds__(256)
void topk_mask_radix(const float* __restrict__ X, const int* __restrict__ KV,
                     us* __restrict__ Mout) {
    const int row  = blockIdx.x * 4 + (threadIdx.x >> 6);
    const int lane = threadIdx.x & 63;
    const float* x = X + (size_t)row * Q_;

    unsigned u[16];
#pragma unroll
    for (int j4 = 0; j4 < 4; ++j4) {
        float4 v = *(const float4*)(x + lane * 16 + j4 * 4);
        float f[4] = {v.x, v.y, v.z, v.w};
#pragma unroll
        for (int e = 0; e < 4; ++e) {
            unsigned fb = __float_as_uint(f[e]);
            u[j4 * 4 + e] = (fb & 0x80000000u) ? ~fb : (fb | 0x80000000u);
        }
    }
    const int k = KV[row];

    unsigned p = 0;
#pragma unroll
    for (int b = 31; b >= 0; --b) {
        unsigned q = p | (1u << b);
        int c = 0;
#pragma unroll
        for (int j = 0; j < 16; ++j) c += (u[j] >= q);
#pragma unroll
        for (int m = 1; m < 64; m <<= 1) c += __shfl_xor(c, m);
        if (c >= k) p = q;
    }

    int gt = 0, eqloc = 0;
#pragma unroll
    for (int j = 0; j < 16; ++j) { gt += (u[j] > p); eqloc += (u[j] == p); }
    int gtot = gt;
#pragma unroll
    for (int m = 1; m < 64; m <<= 1) gtot += __shfl_xor(gtot, m);
    int scan = eqloc;
#pragma unroll
    for (int d = 1; d < 64; d <<= 1) {
        int o = __shfl_up(scan, d);
        if (lane >= d) scan += o;
    }
    int run = scan - eqloc;
    const int quota = k - gtot;

    us m16[16];
#pragma unroll
    for (int j = 0; j < 16; ++j) {
        bool one;
        if (u[j] > p) one = true;
        else if (u[j] == p) { one = (run < quota); ++run; }
        else one = false;
        m16[j] = one ? (us)0x3F80 : (us)0;
    }
    u16x8* dst = (u16x8*)(Mout + (size_t)row * Q_ + lane * 16);
    dst[0] = *(u16x8*)&m16[0];
    dst[1] = *(u16x8*)&m16[8];
}

extern "C" void kernel_launch(void* const* d_in, const int* in_sizes, int n_in,
                              void* d_out, int out_size, void* d_ws, size_t ws_size,
                              hipStream_t stream) {
    const float* x  = (const float*)d_in[0];
    const float* W1 = (const float*)d_in[1];   // [2Q, Q]
    const float* W2 = (const float*)d_in[2];   // [Q, 2Q]
    const float* W3 = (const float*)d_in[3];   // [Q, Q]
    const float* Wc = (const float*)d_in[4];   // [E, Q]
    float* out = (float*)d_out;

    char* ws = (char*)d_ws;
    char* dob = (char*)d_out;
    // ---- ws map (fast path) ----
    us*    H1f  = (us*)ws;                          // pass-1 h1 fp16 [B,2Q] (128M)
    float* SC   = (float*)(ws + ((size_t)128 << 20));// pass-1 scores fp32 (128M)
    us*    H1g0 = (us*)ws;                          // pass-2 h1 hi [CAPF,2Q] (64M)
    us*    H1g1 = (us*)(ws + ((size_t)64 << 20));   // pass-2 h1 lo (64M)
    float* SCg  = (float*)(ws + ((size_t)128 << 20));// pass-2 scores [CAPF,Q] (64M)
    us*    MASKB= (us*)(ws + ((size_t)192 << 20));  // mask bf16 [B,Q] (64M)
    int* KV     = (int*)(ws + ((size_t)256 << 20));
    int* FLAGS  = KV + B_;
    int* CNT    = FLAGS + B_;
    int* CNT2   = CNT + 1;
    int* FLAGS2 = CNT2 + 1;
    // ---- d_out map (scratch until final projection) ----
    us*    Xf   = (us*)dob;                         // x fp16 [B,Q] (64M)
    us*    H2f  = (us*)(dob + ((size_t)64 << 20));  // pass-1 h2 fp16 (64M)
    us*    Xg0  = (us*)dob;                         // gathered x hi (32M)
    us*    Xg1  = (us*)(dob + ((size_t)32 << 20));  // gathered x lo (32M)
    us*    H2g0 = (us*)(dob + ((size_t)64 << 20));  // pass-2 h2 hi (32M)
    us*    H2g1 = (us*)(dob + ((size_t)96 << 20));  // pass-2 h2 lo (32M)
    float* H1F  = (float*)dob;                      // fp64-chain h1 [CAPF2,2Q] (8M)
    float* H2F  = (float*)(dob + ((size_t)8 << 20));
    float* SCF  = (float*)(dob + ((size_t)12 << 20));
    // ---- weight planes (fp16 first, overwritten by bf16 splits) ----
    char* WP = ws + ((size_t)256 << 20) + ((size_t)512 << 10);
    us* W1h = (us*)WP;                       us* W1f = (us*)WP;
    us* W1l = W1h + (size_t)2 * Q_ * Q_;
    us* W2h = W1l + (size_t)2 * Q_ * Q_;     us* W2f = W1l;   // overlaps (dead by then)
    us* W2l = W2h + (size_t)2 * Q_ * Q_;
    us* W3h = W2l + (size_t)2 * Q_ * Q_;     us* W3f = W2h;   // overlaps (dead by then)
    us* W3l = W3h + (size_t)Q_ * Q_;
    us* Wch = W3l + (size_t)Q_ * Q_;
    const size_t NEEDED = ((size_t)256 << 20) + ((size_t)512 << 10) + ((size_t)22 << 20);

    hipMemsetAsync(CNT, 0, 2 * sizeof(int), stream);
    dim3 blk(256);

    if (ws_size >= NEEDED) {
        // --- pass-1: fp16 single-pass selector ---
        cvt_plane_h<<<dim3(2048), blk, 0, stream>>>(x,  Xf,  B_ * Q_ / 8);
        cvt_plane_h<<<dim3(512),  blk, 0, stream>>>(W1, W1f, 2 * Q_ * Q_ / 8);
        cvt_plane_h<<<dim3(512),  blk, 0, stream>>>(W2, W2f, 2 * Q_ * Q_ / 8);
        cvt_plane_h<<<dim3(512),  blk, 0, stream>>>(W3, W3f, Q_ * Q_ / 8);
        gemm4r<1, Q_,     2, true,  true ><<<dim3(1024), dim3(512), 0, stream>>>(
            Xf,  nullptr, W1f, nullptr, H1f, nullptr, 2 * Q_);
        gemm4r<1, 2 * Q_, 2, true,  true ><<<dim3(512),  dim3(512), 0, stream>>>(
            H1f, nullptr, W2f, nullptr, H2f, nullptr, Q_);
        gemm4r<1, Q_,     0, false, true ><<<dim3(512),  dim3(512), 0, stream>>>(
            H2f, nullptr, W3f, nullptr, SC,  nullptr, Q_);
        row_argmax_flag<<<dim3(B_ / 4), blk, 0, stream>>>(SC, KV, FLAGS, CNT, 0.01f);
        // --- pass-2: bf16 3-pass on gathered flagged rows (128^2, 4 blk/CU) ---
        split_planes_k<<<dim3(512), blk, 0, stream>>>(W1, W1h, W1l, 2 * Q_ * Q_ / 8);
        split_planes_k<<<dim3(512), blk, 0, stream>>>(W2, W2h, W2l, 2 * Q_ * Q_ / 8);
        split_planes_k<<<dim3(512), blk, 0, stream>>>(W3, W3h, W3l, Q_ * Q_ / 8);
        cvt_plane_k   <<<dim3(512), blk, 0, stream>>>(Wc, Wch, E_ * Q_ / 8);
        gather_split<<<dim3(2048), blk, 0, stream>>>(x, FLAGS, CNT, Xg0, Xg1);
        gemm_pp<3, true,  true,  true><<<dim3((CAPF / 128) * (2 * Q_ / 128)), blk, 0, stream>>>(
            Xg0,  Xg1,  W1h, W1l, H1g0, H1g1, 2 * Q_, Q_, CNT);
        gemm_pp<3, true,  true,  true><<<dim3((CAPF / 128) * (Q_ / 128)), blk, 0, stream>>>(
            H1g0, H1g1, W2h, W2l, H2g0, H2g1, Q_, 2 * Q_, CNT);
        gemm_pp<3, false, false, true><<<dim3((CAPF / 128) * (Q_ / 128)), blk, 0, stream>>>(
            H2g0, H2g1, W3h, W3l, SCg, nullptr, Q_, Q_, CNT);
        g_argmax_flag2<<<dim3(1024), blk, 0, stream>>>(SCg, FLAGS, CNT, KV, FLAGS2, CNT2);
        // --- pass-3: fp64 exact rescore of pass-2 near-ties ---
        rescore_gemm<Q_,     true,  true ><<<dim3(4096), blk, 0, stream>>>(x,   W1, H1F, FLAGS2, CNT2, 2 * Q_, CAPF2);
        rescore_gemm<2 * Q_, false, true ><<<dim3(2048), blk, 0, stream>>>(H1F, W2, H2F, FLAGS2, CNT2, Q_,     CAPF2);
        rescore_gemm<Q_,     false, false><<<dim3(2048), blk, 0, stream>>>(H2F, W3, SCF, FLAGS2, CNT2, Q_,     CAPF2);
        rescore_argmax<<<dim3(64), blk, 0, stream>>>(SCF, FLAGS2, CNT2, KV, CAPF2);
        // --- mask + projection ---
        topk_mask_radix<<<dim3(B_ / 4), blk, 0, stream>>>(x, KV, MASKB);
        gemm4r<1, Q_, 0, false, false><<<dim3(512), dim3(512), 0, stream>>>(
            MASKB, nullptr, Wch, nullptr, out, nullptr, E_);
    } else {
        // fallback: round-4 path (in-kernel split, fp32 weights)
        us*    H1_0 = (us*)ws;
        us*    H1_1 = (us*)(ws + ((size_t)128 << 20));
        float* SCo  = (float*)ws;
        us*    MB   = (us*)(ws + ((size_t)128 << 20));
        us* H2_0 = (us*)d_out;
        us* H2_1 = (us*)d_out + (size_t)B_ * Q_;
        float* H1Fo = (float*)ws;
        float* H2Fo = (float*)(ws + ((size_t)128 << 20));
        float* SCFo = (float*)(ws + ((size_t)192 << 20));
        gemm3p<3, true,  true,  true ><<<dim3(2 * Q_ / 128, B_ / 128), blk, 0, stream>>>(
            x, nullptr, W1, H1_0, H1_1, B_, 2 * Q_, Q_);
        gemm3p<3, false, true,  true ><<<dim3(Q_ / 128, B_ / 128), blk, 0, stream>>>(
            H1_0, H1_1, W2, H2_0, H2_1, B_, Q_, 2 * Q_);
        gemm3p<3, false, false, false><<<dim3(Q_ / 128, B_ / 128), blk, 0, stream>>>(
            H2_0, H2_1, W3, SCo, nullptr, B_, Q_, Q_);
        row_argmax_flag<<<dim3(B_ / 4), blk, 0, stream>>>(SCo, KV, FLAGS, CNT, 1e-3f);
        rescore_gemm<Q_,     true,  true ><<<dim3(4096), blk, 0, stream>>>(x,    W1, H1Fo, FLAGS, CNT, 2 * Q_, CAPF);
        rescore_gemm<2 * Q_, false, true ><<<dim3(2048), blk, 0, stream>>>(H1Fo, W2, H2Fo, FLAGS, CNT, Q_,     CAPF);
        rescore_gemm<Q_,     false, false><<<dim3(2048), blk, 0, stream>>>(H2Fo, W3, SCFo, FLAGS, CNT, Q_,     CAPF);
        rescore_argmax<<<dim3(64), blk, 0, stream>>>(SCFo, FLAGS, CNT, KV, CAPF);
        topk_mask_radix<<<dim3(B_ / 4), blk, 0, stream>>>(x, KV, MB);
        gemm3p<1, false, false, false><<<dim3(E_ / 128, B_ / 128), blk, 0, stream>>>(
            MB, nullptr, Wc, out, nullptr, B_, E_, Q_);
    }
}

// Round 13
// 1080.031 us; speedup vs baseline: 1.2021x; 1.2021x over previous
//
#include <hip/hip_runtime.h>
#include <stdint.h>

#define B_  32768
#define Q_  1024
#define E_  1024
#define CAPF  4096    // stage-1 flag capacity (expected ~2400, 34-sigma headroom)
#define CAPF2 1024    // stage-2 flag capacity (rows refined by fp64)

typedef __attribute__((ext_vector_type(8))) short bf16x8;
typedef __attribute__((ext_vector_type(8))) _Float16 f16x8;
typedef __attribute__((ext_vector_type(8))) unsigned short u16x8;
typedef __attribute__((ext_vector_type(4))) float f32x4;
typedef unsigned short us;

__device__ __forceinline__ f32x4 MFMA16(bf16x8 a, bf16x8 b, f32x4 c) {
    return __builtin_amdgcn_mfma_f32_16x16x32_bf16(a, b, c, 0, 0, 0);
}
__device__ __forceinline__ f32x4 MFMA16H(bf16x8 a, bf16x8 b, f32x4 c) {
    return __builtin_amdgcn_mfma_f32_16x16x32_f16(
        __builtin_bit_cast(f16x8, a), __builtin_bit_cast(f16x8, b), c, 0, 0, 0);
}

__device__ __forceinline__ us f2bf(float v) {   // RNE fp32->bf16
    unsigned u = __float_as_uint(v);
    u += 0x7FFFu + ((u >> 16) & 1u);
    return (us)(u >> 16);
}
__device__ __forceinline__ float bf2f(us b) {
    return __uint_as_float(((unsigned)b) << 16);
}
__device__ __forceinline__ us f2h(float v) {    // RNE fp32->fp16 bits
    _Float16 h = (_Float16)v;
    return __builtin_bit_cast(unsigned short, h);
}

// ---------------- plane prep kernels (memory-bound, run once) ---------------
__global__ __launch_bounds__(256)
void split_planes_k(const float* __restrict__ in, us* __restrict__ hi,
                    us* __restrict__ lo, int n8) {
    int i = blockIdx.x * 256 + threadIdx.x;
    const int stride = gridDim.x * 256;
    for (; i < n8; i += stride) {
        float4 a = ((const float4*)in)[i * 2];
        float4 b = ((const float4*)in)[i * 2 + 1];
        float f[8] = {a.x, a.y, a.z, a.w, b.x, b.y, b.z, b.w};
        u16x8 h, l;
#pragma unroll
        for (int j = 0; j < 8; ++j) {
            us c0 = f2bf(f[j]);
            h[j] = c0;
            l[j] = f2bf(f[j] - bf2f(c0));   // exact residual (Sterbenz)
        }
        ((u16x8*)hi)[i] = h;
        ((u16x8*)lo)[i] = l;
    }
}

__global__ __launch_bounds__(256)
void cvt_plane_k(const float* __restrict__ in, us* __restrict__ hi, int n8) {
    int i = blockIdx.x * 256 + threadIdx.x;
    const int stride = gridDim.x * 256;
    for (; i < n8; i += stride) {
        float4 a = ((const float4*)in)[i * 2];
        float4 b = ((const float4*)in)[i * 2 + 1];
        float f[8] = {a.x, a.y, a.z, a.w, b.x, b.y, b.z, b.w};
        u16x8 h;
#pragma unroll
        for (int j = 0; j < 8; ++j) h[j] = f2bf(f[j]);
        ((u16x8*)hi)[i] = h;
    }
}

__global__ __launch_bounds__(256)
void cvt_plane_h(const float* __restrict__ in, us* __restrict__ hi, int n8) {
    int i = blockIdx.x * 256 + threadIdx.x;
    const int stride = gridDim.x * 256;
    for (; i < n8; i += stride) {
        float4 a = ((const float4*)in)[i * 2];
        float4 b = ((const float4*)in)[i * 2 + 1];
        float f[8] = {a.x, a.y, a.z, a.w, b.x, b.y, b.z, b.w};
        u16x8 h;
#pragma unroll
        for (int j = 0; j < 8; ++j) h[j] = f2h(f[j]);
        ((u16x8*)hi)[i] = h;
    }
}

// gather flagged rows of fp32 x and split into bf16 hi/lo planes [CAPF][Q]
__global__ __launch_bounds__(256)
void gather_split(const float* __restrict__ X, const int* __restrict__ flags,
                  const int* __restrict__ cnt, us* __restrict__ G0,
                  us* __restrict__ G1) {
    const int n = min(*cnt, CAPF);
    for (int it = blockIdx.x; it < n; it += gridDim.x) {
        int row = flags[it];
        if ((unsigned)row >= B_) row = 0;            // replay-safety clamp
        float4 v = ((const float4*)(X + (size_t)row * Q_))[threadIdx.x];
        float f[4] = {v.x, v.y, v.z, v.w};
        us h[4], l[4];
#pragma unroll
        for (int j = 0; j < 4; ++j) {
            h[j] = f2bf(f[j]);
            l[j] = f2bf(f[j] - bf2f(h[j]));
        }
        *(uint2*)&G0[(size_t)it * Q_ + threadIdx.x * 4] = *(uint2*)h;
        *(uint2*)&G1[(size_t)it * Q_ + threadIdx.x * 4] = *(uint2*)l;
    }
}

// sum SPLITS fp32 partials; MODE 0: fp32 out; MODE 1: relu + bf16 hi/lo planes
template<int SPLITS, int MODE>
__global__ __launch_bounds__(256)
void finalize_k(const float* __restrict__ P, size_t pstride,
                us* __restrict__ o0, us* __restrict__ o1,
                float* __restrict__ of, const int* __restrict__ cnt, int N) {
    const int n = min(*cnt, CAPF);
    const int total4 = n * (N >> 2);
    int i = blockIdx.x * 256 + threadIdx.x;
    const int stride = gridDim.x * 256;
    for (; i < total4; i += stride) {
        float4 s = ((const float4*)P)[i];
#pragma unroll
        for (int sp = 1; sp < SPLITS; ++sp) {
            float4 p = *(const float4*)(P + (size_t)sp * pstride + (size_t)i * 4);
            s.x += p.x; s.y += p.y; s.z += p.z; s.w += p.w;
        }
        if constexpr (MODE == 0) {
            ((float4*)of)[i] = s;
        } else {
            float f[4] = {fmaxf(s.x, 0.f), fmaxf(s.y, 0.f),
                          fmaxf(s.z, 0.f), fmaxf(s.w, 0.f)};
            us h[4], l[4];
#pragma unroll
            for (int j = 0; j < 4; ++j) {
                h[j] = f2bf(f[j]);
                l[j] = f2bf(f[j] - bf2f(h[j]));
            }
            *(uint2*)&o0[(size_t)i * 4] = *(uint2*)h;
            *(uint2*)&o1[(size_t)i * 4] = *(uint2*)l;
        }
    }
}

// ============================================================================
// 256x256-tile GEMM (round-8 verified core). 8 waves (2Mx4N), BK=32, 4-slot
// whole-tile LDS ring (128 KiB), safe deep pipeline:
//   half-step: RD(frags t+1) || stage(t+4, clamped) || MFMA(t)
//              -> lgkmcnt(0) -> vmcnt(8) -> s_barrier
// NSEG=3: acc = A0B0 + A0B1 + A1B0 over K'=3K (fp32-grade split-bf16).
// EMIT: 0=fp32, 1=bf16 hi/lo pair, 2=fp16. FP16: f16 MFMA.
// ============================================================================
#define LGKM0() asm volatile("s_waitcnt lgkmcnt(0)" ::: "memory")
#define VMC8()  asm volatile("s_waitcnt vmcnt(8)" ::: "memory")
#define BAR()   __builtin_amdgcn_s_barrier()
#define RD_AB(Aarr, Barr, slot) { \
    const us* _la = &LA[(slot) * 8192]; const us* _lb = &LB[(slot) * 8192]; \
    _Pragma("unroll") for (int mf = 0; mf < 8; ++mf) Aarr[mf] = *(const bf16x8*)&_la[ago[mf]]; \
    _Pragma("unroll") for (int nf = 0; nf < 4; ++nf) Barr[nf] = *(const bf16x8*)&_lb[bgo[nf]]; }
#define CLX(AF, BF) { __builtin_amdgcn_s_setprio(1); \
    _Pragma("unroll") for (int mf = 0; mf < 8; ++mf) { \
        _Pragma("unroll") for (int nf = 0; nf < 4; ++nf) { \
            if constexpr (FP16) acc[mf][nf] = MFMA16H(AF[mf], BF[nf], acc[mf][nf]); \
            else               acc[mf][nf] = MFMA16 (AF[mf], BF[nf], acc[mf][nf]); } } \
    __builtin_amdgcn_s_setprio(0); }

template<int NSEG, int K, int EMIT, bool RELU, bool FP16>
__global__ __launch_bounds__(512, 2)
void gemm4r(const us* __restrict__ A0p, const us* __restrict__ A1p,
            const us* __restrict__ B0p, const us* __restrict__ B1p,
            void* __restrict__ Cp0, void* __restrict__ Cp1, int N) {
    constexpr int TPS = K / 32;
    constexpr int NT  = NSEG * TPS;
    static_assert(NT % 2 == 0 && NT >= 4, "shape");
    __shared__ __align__(16) us LA[4 * 8192];
    __shared__ __align__(16) us LB[4 * 8192];

    const int t = threadIdx.x;
    const int wv = t >> 6, lane = t & 63;
    const int lanelo = lane & 15, kq = lane >> 4;
    const int wm = wv >> 2, wn = wv & 3;

    const int q8 = gridDim.x >> 3;       // grid % 8 == 0 (T1 bijective swizzle)
    const int logical = ((int)blockIdx.x & 7) * q8 + ((int)blockIdx.x >> 3);
    const int gx = N >> 8;
    const int m0 = (logical / gx) * 256, n0 = (logical % gx) * 256;

    int soff[2], ldst[2];
#pragma unroll
    for (int i = 0; i < 2; ++i) {
        int s = i * 512 + t;
        int row = s >> 2, c = s & 3;
        soff[i] = row * K + (c ^ ((row >> 1) & 3)) * 8;
        ldst[i] = (i * 512 + wv * 64) * 8;
    }
    int ago[8], bgo[4];
#pragma unroll
    for (int mf = 0; mf < 8; ++mf) {
        int row = wm * 128 + mf * 16 + lanelo;
        ago[mf] = (row * 4 + (kq ^ ((row >> 1) & 3))) * 8;
    }
#pragma unroll
    for (int nf = 0; nf < 4; ++nf) {
        int row = wn * 64 + nf * 16 + lanelo;
        bgo[nf] = (row * 4 + (kq ^ ((row >> 1) & 3))) * 8;
    }

    auto stage = [&](int tv) {
        int slot = tv & 3;
        int seg = tv / TPS;
        int kb  = (tv - seg * TPS) * 32;
        const us* Ap = (NSEG == 1 || seg < 2) ? A0p : A1p;
        const us* Bp = (NSEG == 3 && seg == 1) ? B1p : B0p;
        const us* Abase = Ap + (size_t)m0 * K + kb;
        const us* Bbase = Bp + (size_t)n0 * K + kb;
        us* dA = &LA[slot * 8192];
        us* dB = &LB[slot * 8192];
#pragma unroll
        for (int i = 0; i < 2; ++i) {
            __builtin_amdgcn_global_load_lds(
                (const __attribute__((address_space(1))) void*)(Abase + soff[i]),
                (__attribute__((address_space(3))) void*)(dA + ldst[i]), 16, 0, 0);
            __builtin_amdgcn_global_load_lds(
                (const __attribute__((address_space(1))) void*)(Bbase + soff[i]),
                (__attribute__((address_space(3))) void*)(dB + ldst[i]), 16, 0, 0);
        }
    };

    f32x4 acc[8][4];
#pragma unroll
    for (int i = 0; i < 8; ++i)
#pragma unroll
        for (int j = 0; j < 4; ++j) acc[i][j] = (f32x4){0.f, 0.f, 0.f, 0.f};

    bf16x8 aE[8], bE[4], aO[8], bO[4];

    stage(0); stage(1); stage(2);
    VMC8();  BAR();
    RD_AB(aE, bE, 0);
    stage(3);
    LGKM0(); VMC8(); BAR();

    for (int tt = 0; tt < NT; tt += 2) {
        RD_AB(aO, bO, (tt + 1) & 3);
        { int tv = tt + 4; if (tv > NT - 1) tv = NT - 1; stage(tv); }
        CLX(aE, bE);
        LGKM0(); VMC8(); BAR();
        { int tn = (tt + 2 < NT) ? (tt + 2) : (NT - 1);
          RD_AB(aE, bE, tn & 3); }
        { int tv = tt + 5; if (tv > NT - 1) tv = NT - 1; stage(tv); }
        CLX(aO, bO);
        LGKM0(); VMC8(); BAR();
    }

    // epilogue: C/D layout col=lane&15, row=(lane>>4)*4+reg (m89/m91)
#pragma unroll
    for (int mf = 0; mf < 8; ++mf)
#pragma unroll
        for (int nf = 0; nf < 4; ++nf)
#pragma unroll
            for (int r = 0; r < 4; ++r) {
                int row = m0 + wm * 128 + mf * 16 + kq * 4 + r;
                int col = n0 + wn * 64 + nf * 16 + lanelo;
                float v = acc[mf][nf][r];
                if constexpr (RELU) v = fmaxf(v, 0.f);
                if constexpr (EMIT == 1) {
                    us c0 = f2bf(v);
                    ((us*)Cp0)[(size_t)row * N + col] = c0;
                    ((us*)Cp1)[(size_t)row * N + col] = f2bf(v - bf2f(c0));
                } else if constexpr (EMIT == 2) {
                    ((us*)Cp0)[(size_t)row * N + col] = f2h(v);
                } else {
                    ((float*)Cp0)[(size_t)row * N + col] = v;
                }
            }
}

// ============================================================================
// 128x128-tile split-K all-plane GEMM for the gathered pass. grid.y = split.
// Split s computes real-K [s*K/S,(s+1)*K/S) of all NSEG segments into fp32
// partial P + s*pstride. DYN early-exit on m-tiles beyond ceil(n/128).
// Verified swizzle pair ((row>>1)&3) both sides -> 0 bank conflicts.
// ============================================================================
template<int NPASS, int SPLITS>
__global__ __launch_bounds__(256, 4)
void gemm_sp(const us* __restrict__ A0, const us* __restrict__ A1,
             const us* __restrict__ B0, const us* __restrict__ B1,
             float* __restrict__ P, size_t pstride,
             int N, int K, const int* __restrict__ ncnt) {
    __shared__ __align__(16) us A0s[128 * 32];
    __shared__ __align__(16) us B0s[128 * 32];
    __shared__ __align__(16) us A1s[(NPASS == 3) ? 128 * 32 : 8];
    __shared__ __align__(16) us B1s[(NPASS == 3) ? 128 * 32 : 8];

    const int t = threadIdx.x;
    const int wave = t >> 6, lane = t & 63;
    const int lanelo = lane & 15, kq = lane >> 4;
    const int wm = wave >> 1, wn = wave & 1;
    const int q8 = gridDim.x >> 3;                 // grid.x divisible by 8
    const int logical = ((int)blockIdx.x & 7) * q8 + ((int)blockIdx.x >> 3);
    const int gx = N >> 7;
    const int m0 = (logical / gx) * 128, n0 = (logical % gx) * 128;
    const int split = blockIdx.y;

    int nn = *ncnt; if (nn > CAPF) nn = CAPF;
    if (m0 >= ((nn + 127) & ~127)) return;

    const int Ks = K / SPLITS;
    const int kbase = split * Ks;
    const int tps = Ks >> 5;

    f32x4 acc[4][4];
#pragma unroll
    for (int i = 0; i < 4; ++i)
#pragma unroll
        for (int j = 0; j < 4; ++j) acc[i][j] = (f32x4){0.f, 0.f, 0.f, 0.f};

    for (int vt = 0; vt < NPASS * tps; ++vt) {
        const int seg = vt / tps;
        const int kt  = kbase + (vt - seg * tps) * 32;
        const us* Ap = (NPASS == 1 || seg < 2) ? A0 : A1;
        const us* Bp = (NPASS == 3 && seg == 1) ? B1 : B0;
        __syncthreads();
#pragma unroll
        for (int g = 0; g < 2; ++g) {
            int c = (g * 4 + wave) * 64 + lane;
            int row = c >> 2;
            int koff = (c & 3) ^ ((row >> 1) & 3);   // pre-swizzled source
            size_t offa = (size_t)(m0 + row) * K + kt + koff * 8;
            size_t offb = (size_t)(n0 + row) * K + kt + koff * 8;
            int dst = (g * 4 + wave) * 512;
            __builtin_amdgcn_global_load_lds(
                (const __attribute__((address_space(1))) void*)(Ap + offa),
                (__attribute__((address_space(3))) void*)&A0s[dst], 16, 0, 0);
            __builtin_amdgcn_global_load_lds(
                (const __attribute__((address_space(1))) void*)(Bp + offb),
                (__attribute__((address_space(3))) void*)&B0s[dst], 16, 0, 0);
        }
        __syncthreads();

        bf16x8 a0[4];
#pragma unroll
        for (int mf = 0; mf < 4; ++mf) {
            int ar = wm * 64 + mf * 16 + lanelo;
            int ac = ar * 4 + (kq ^ ((ar >> 1) & 3));
            a0[mf] = *(const bf16x8*)&A0s[ac * 8];
        }
#pragma unroll
        for (int nf = 0; nf < 4; ++nf) {
            int br = wn * 64 + nf * 16 + lanelo;
            int bc = br * 4 + (kq ^ ((br >> 1) & 3));
            bf16x8 vb0 = *(const bf16x8*)&B0s[bc * 8];
#pragma unroll
            for (int mf = 0; mf < 4; ++mf) acc[mf][nf] = MFMA16(a0[mf], vb0, acc[mf][nf]);
        }
    }

    float* Pd = P + (size_t)split * pstride;
#pragma unroll
    for (int mf = 0; mf < 4; ++mf)
#pragma unroll
        for (int nf = 0; nf < 4; ++nf)
#pragma unroll
            for (int r = 0; r < 4; ++r) {
                int row = m0 + wm * 64 + mf * 16 + kq * 4 + r;
                int col = n0 + wn * 64 + nf * 16 + lanelo;
                Pd[(size_t)row * N + col] = acc[mf][nf][r];
            }
}

// ---------------- fallback GEMM (round-4 path, in-kernel split) -------------
__device__ __forceinline__ int chunk_of(int row, int koff) {
    return row * 4 + (koff ^ (row & 3));
}

template<int NPASS>
__device__ __forceinline__ void split_store(us* S0, us* S1,
                                            int rowX, int koffX, float4 a, float4 b) {
    int ch = chunk_of(rowX, koffX);
    float f[8] = {a.x, a.y, a.z, a.w, b.x, b.y, b.z, b.w};
    bf16x8 lo, hi;
#pragma unroll
    for (int j = 0; j < 8; ++j) {
        us c0 = f2bf(f[j]);
        lo[j] = (short)c0;
        hi[j] = (short)f2bf(f[j] - bf2f(c0));
    }
    *(bf16x8*)&S0[ch * 8] = lo;
    if constexpr (NPASS == 3) *(bf16x8*)&S1[ch * 8] = hi;
}

template<int NPASS, bool AF32, bool RELU, bool EMITP>
__global__ __launch_bounds__(256, 2)
void gemm3p(const void* __restrict__ Ap0, const void* __restrict__ Ap1,
            const float* __restrict__ Wf,
            void* __restrict__ Cp0, void* __restrict__ Cp1,
            int M, int N, int K) {
    __shared__ __align__(16) us A0s[128 * 32];
    __shared__ __align__(16) us B0s[128 * 32];
    __shared__ __align__(16) us A1s[(NPASS == 3) ? 128 * 32 : 8];
    __shared__ __align__(16) us B1s[(NPASS == 3) ? 128 * 32 : 8];

    const int t = threadIdx.x;
    const int wave = t >> 6, lane = t & 63;
    const int lanelo = lane & 15, kq = lane >> 4;
    const int wm = wave >> 1, wn = wave & 1;
    const int m0 = blockIdx.y * 128, n0 = blockIdx.x * 128;
    const int brow = t >> 1, bhalf = t & 1;

    f32x4 acc[4][4];
#pragma unroll
    for (int i = 0; i < 4; ++i)
#pragma unroll
        for (int j = 0; j < 4; ++j) acc[i][j] = (f32x4){0.f, 0.f, 0.f, 0.f};

    for (int kt = 0; kt < K; kt += 32) {
        __syncthreads();
        const float* wp = Wf + (size_t)(n0 + brow) * K + kt + bhalf * 16;
        float4 v0 = *(const float4*)(wp + 0);
        float4 v1 = *(const float4*)(wp + 4);
        float4 v2 = *(const float4*)(wp + 8);
        float4 v3 = *(const float4*)(wp + 12);
        if constexpr (AF32) {
            const float* ap = (const float*)Ap0 + (size_t)(m0 + brow) * K + kt + bhalf * 16;
            float4 u0 = *(const float4*)(ap + 0);
            float4 u1 = *(const float4*)(ap + 4);
            float4 u2 = *(const float4*)(ap + 8);
            float4 u3 = *(const float4*)(ap + 12);
            split_store<NPASS>(A0s, A1s, brow, bhalf * 2 + 0, u0, u1);
            split_store<NPASS>(A0s, A1s, brow, bhalf * 2 + 1, u2, u3);
        } else {
#pragma unroll
            for (int g = 0; g < 2; ++g) {
                int c = (g * 4 + wave) * 64 + lane;
                int row = c >> 2;
                int koff = (c & 3) ^ (row & 3);
                const us* s0 = (const us*)Ap0 + (size_t)(m0 + row) * K + kt + koff * 8;
                __builtin_amdgcn_global_load_lds(
                    (const __attribute__((address_space(1))) void*)s0,
                    (__attribute__((address_space(3))) void*)&A0s[(size_t)(g * 4 + wave) * 512],
                    16, 0, 0);
                if constexpr (NPASS == 3) {
                    const us* s1 = (const us*)Ap1 + (size_t)(m0 + row) * K + kt + koff * 8;
                    __builtin_amdgcn_global_load_lds(
                        (const __attribute__((address_space(1))) void*)s1,
                        (__attribute__((address_space(3))) void*)&A1s[(size_t)(g * 4 + wave) * 512],
                        16, 0, 0);
                }
            }
        }
        split_store<NPASS>(B0s, B1s, brow, bhalf * 2 + 0, v0, v1);
        split_store<NPASS>(B0s, B1s, brow, bhalf * 2 + 1, v2, v3);
        __syncthreads();

        bf16x8 a0[4], a1[4];
#pragma unroll
        for (int mf = 0; mf < 4; ++mf) {
            int ar = wm * 64 + mf * 16 + lanelo;
            int ac = chunk_of(ar, kq);
            a0[mf] = *(const bf16x8*)&A0s[ac * 8];
            if constexpr (NPASS == 3) a1[mf] = *(const bf16x8*)&A1s[ac * 8];
        }
#pragma unroll
        for (int nf = 0; nf < 4; ++nf) {
            int br = wn * 64 + nf * 16 + lanelo;
            int bc = chunk_of(br, kq);
            bf16x8 vb0 = *(const bf16x8*)&B0s[bc * 8];
#pragma unroll
            for (int mf = 0; mf < 4; ++mf) acc[mf][nf] = MFMA16(a0[mf], vb0, acc[mf][nf]);
            if constexpr (NPASS == 3) {
                bf16x8 vb1 = *(const bf16x8*)&B1s[bc * 8];
#pragma unroll
                for (int mf = 0; mf < 4; ++mf) acc[mf][nf] = MFMA16(a0[mf], vb1, acc[mf][nf]);
#pragma unroll
                for (int mf = 0; mf < 4; ++mf) acc[mf][nf] = MFMA16(a1[mf], vb0, acc[mf][nf]);
            }
        }
    }

#pragma unroll
    for (int mf = 0; mf < 4; ++mf)
#pragma unroll
        for (int nf = 0; nf < 4; ++nf)
#pragma unroll
            for (int r = 0; r < 4; ++r) {
                int row = m0 + wm * 64 + mf * 16 + kq * 4 + r;
                int col = n0 + wn * 64 + nf * 16 + lanelo;
                float v = acc[mf][nf][r];
                if constexpr (RELU) v = fmaxf(v, 0.f);
                if constexpr (EMITP) {
                    us c0 = f2bf(v);
                    ((us*)Cp0)[(size_t)row * N + col] = c0;
                    ((us*)Cp1)[(size_t)row * N + col] = f2bf(v - bf2f(c0));
                } else {
                    ((float*)Cp0)[(size_t)row * N + col] = v;
                }
            }
}

// k[row] = argmax+1 (first occurrence); flag rows whose top-2 gap < theta
__global__ __launch_bounds__(256)
void row_argmax_flag(const float* __restrict__ S, int* __restrict__ KV,
                     int* __restrict__ flags, int* __restrict__ cnt, float theta) {
    int row = blockIdx.x * 4 + (threadIdx.x >> 6);
    int lane = threadIdx.x & 63;
    const float* s = S + (size_t)row * Q_;
    float b1 = -3.4e38f, b2 = -3.4e38f; int i1 = 0;
    for (int j = lane; j < Q_; j += 64) {
        float v = s[j];
        if (v > b1) { b2 = b1; b1 = v; i1 = j; }
        else if (v > b2) b2 = v;
    }
#pragma unroll
    for (int m = 1; m < 64; m <<= 1) {
        float o1 = __shfl_xor(b1, m);
        int   oi = __shfl_xor(i1, m);
        float o2 = __shfl_xor(b2, m);
        if (o1 > b1 || (o1 == b1 && oi < i1)) {
            b2 = fmaxf(b1, o2);
            b1 = o1; i1 = oi;
        } else {
            b2 = fmaxf(b2, o1);
        }
    }
    if (lane == 0) {
        KV[row] = i1 + 1;
        if (b1 - b2 < theta) {
            int p = atomicAdd(cnt, 1);
            if (p < CAPF) flags[p] = row;
        }
    }
}

// argmax over gathered (pass-2) scores: scatter k, flag near-ties for fp64
__global__ __launch_bounds__(256)
void g_argmax_flag2(const float* __restrict__ SCg, const int* __restrict__ flags,
                    const int* __restrict__ cnt, int* __restrict__ KV,
                    int* __restrict__ flags2, int* __restrict__ cnt2) {
    const int lane = threadIdx.x & 63, wv = threadIdx.x >> 6;
    const int n = min(*cnt, CAPF);
    for (int it = blockIdx.x * 4 + wv; it < n; it += gridDim.x * 4) {
        const float* s = SCg + (size_t)it * Q_;
        float b1 = -3.4e38f, b2 = -3.4e38f; int i1 = 0;
        for (int j = lane; j < Q_; j += 64) {
            float v = s[j];
            if (v > b1) { b2 = b1; b1 = v; i1 = j; }
            else if (v > b2) b2 = v;
        }
#pragma unroll
        for (int m = 1; m < 64; m <<= 1) {
            float o1 = __shfl_xor(b1, m);
            int   oi = __shfl_xor(i1, m);
            float o2 = __shfl_xor(b2, m);
            if (o1 > b1 || (o1 == b1 && oi < i1)) {
                b2 = fmaxf(b1, o2);
                b1 = o1; i1 = oi;
            } else {
                b2 = fmaxf(b2, o1);
            }
        }
        if (lane == 0) {
            int r = flags[it];
            if ((unsigned)r < B_) {
                KV[r] = i1 + 1;
                if (b1 - b2 < 1e-3f) {
                    int p = atomicAdd(cnt2, 1);
                    if (p < CAPF2) flags2[p] = r;
                }
            }
        }
    }
}

// ---- parallel coalesced rescore (fp64): K compile-time, float4 loads ----
template<int K, bool IN_BY_FLAG, bool RELU>
__global__ __launch_bounds__(256)
void rescore_gemm(const float* __restrict__ IN, const float* __restrict__ W,
                  float* __restrict__ OUT, const int* __restrict__ flags,
                  const int* __restrict__ cnt, int N, int cap) {
    __shared__ float xr[K];
    const int t = threadIdx.x, lane = t & 63, wv = t >> 6;
    const int n = min(*cnt, cap);
    const int chunks = N >> 4;
    for (int w = blockIdx.x; w < n * chunks; w += gridDim.x) {
        const int it = w / chunks, ch = w - it * chunks;
        int srow = IN_BY_FLAG ? flags[it] : it;
        if (IN_BY_FLAG && (unsigned)srow >= B_) srow = 0;   // replay-safety clamp
        const float* rp = IN + (size_t)srow * K;
        __syncthreads();
#pragma unroll
        for (int p = t; p < K / 4; p += 256)
            ((float4*)xr)[p] = ((const float4*)rp)[p];
        __syncthreads();
#pragma unroll
        for (int jj = 0; jj < 4; ++jj) {
            const int col = ch * 16 + wv * 4 + jj;
            const float* wr = W + (size_t)col * K;
            double a0 = 0.0, a1 = 0.0;
#pragma unroll
            for (int i = 0; i < K / 256; ++i) {
                const int k = i * 256 + lane * 4;
                float4 w4 = *(const float4*)(wr + k);
                float4 x4 = *(const float4*)(xr + k);
                a0 += (double)x4.x * w4.x + (double)x4.y * w4.y;
                a1 += (double)x4.z * w4.z + (double)x4.w * w4.w;
            }
            double a = a0 + a1;
#pragma unroll
            for (int m = 1; m < 64; m <<= 1) a += __shfl_xor(a, m);
            if (lane == 0) {
                float v = (float)a;
                if (RELU) v = fmaxf(v, 0.f);
                OUT[(size_t)it * N + col] = v;
            }
        }
    }
}

// final exact argmax over fp64-rescored rows, first-occurrence tie-break
__global__ __launch_bounds__(256)
void rescore_argmax(const float* __restrict__ SCF, const int* __restrict__ flags,
                    const int* __restrict__ cnt, int* __restrict__ KV, int cap) {
    const int lane = threadIdx.x & 63, wv = threadIdx.x >> 6;
    const int n = min(*cnt, cap);
    for (int it = blockIdx.x * 4 + wv; it < n; it += gridDim.x * 4) {
        const float* s = SCF + (size_t)it * Q_;
        float best = -3.4e38f; int bi = 0;
        for (int j = lane; j < Q_; j += 64) {
            float v = s[j];
            if (v > best) { best = v; bi = j; }
        }
#pragma unroll
        for (int m = 1; m < 64; m <<= 1) {
            float ov = __shfl_xor(best, m); int oi = __shfl_xor(bi, m);
            if (ov > best || (ov == best && oi < bi)) { best = ov; bi = oi; }
        }
        if (lane == 0) {
            int r = flags[it];
            if ((unsigned)r < B_) KV[r] = bi + 1;
        }
    }
}

// ---- stable top-k mask via in-register bit-descent radix select ----
__global__ __launch_bounds__(256)
void topk_mask_radix(const float* __restrict__ X, const int* __restrict__ KV,
                     us* __restrict__ Mout) {
    const int row  = blockIdx.x * 4 + (threadIdx.x >> 6);
    const int lane = threadIdx.x & 63;
    const float* x = X + (size_t)row * Q_;

    unsigned u[16];
#pragma unroll
    for (int j4 = 0; j4 < 4; ++j4) {
        float4 v = *(const float4*)(x + lane * 16 + j4 * 4);
        float f[4] = {v.x, v.y, v.z, v.w};
#pragma unroll
        for (int e = 0; e < 4; ++e) {
            unsigned fb = __float_as_uint(f[e]);
            u[j4 * 4 + e] = (fb & 0x80000000u) ? ~fb : (fb | 0x80000000u);
        }
    }
    const int k = KV[row];

    unsigned p = 0;
#pragma unroll
    for (int b = 31; b >= 0; --b) {
        unsigned q = p | (1u << b);
        int c = 0;
#pragma unroll
        for (int j = 0; j < 16; ++j) c += (u[j] >= q);
#pragma unroll
        for (int m = 1; m < 64; m <<= 1) c += __shfl_xor(c, m);
        if (c >= k) p = q;
    }

    int gt = 0, eqloc = 0;
#pragma unroll
    for (int j = 0; j < 16; ++j) { gt += (u[j] > p); eqloc += (u[j] == p); }
    int gtot = gt;
#pragma unroll
    for (int m = 1; m < 64; m <<= 1) gtot += __shfl_xor(gtot, m);
    int scan = eqloc;
#pragma unroll
    for (int d = 1; d < 64; d <<= 1) {
        int o = __shfl_up(scan, d);
        if (lane >= d) scan += o;
    }
    int run = scan - eqloc;
    const int quota = k - gtot;

    us m16[16];
#pragma unroll
    for (int j = 0; j < 16; ++j) {
        bool one;
        if (u[j] > p) one = true;
        else if (u[j] == p) { one = (run < quota); ++run; }
        else one = false;
        m16[j] = one ? (us)0x3F80 : (us)0;
    }
    u16x8* dst = (u16x8*)(Mout + (size_t)row * Q_ + lane * 16);
    dst[0] = *(u16x8*)&m16[0];
    dst[1] = *(u16x8*)&m16[8];
}

extern "C" void kernel_launch(void* const* d_in, const int* in_sizes, int n_in,
                              void* d_out, int out_size, void* d_ws, size_t ws_size,
                              hipStream_t stream) {
    const float* x  = (const float*)d_in[0];
    const float* W1 = (const float*)d_in[1];   // [2Q, Q]
    const float* W2 = (const float*)d_in[2];   // [Q, 2Q]
    const float* W3 = (const float*)d_in[3];   // [Q, Q]
    const float* Wc = (const float*)d_in[4];   // [E, Q]
    float* out = (float*)d_out;

    char* ws = (char*)d_ws;
    char* dob = (char*)d_out;
    // ---- ws map (fast path) ----
    us*    H1f  = (us*)ws;                          // pass-1 h1 fp16 [B,2Q] (128M)
    float* SC   = (float*)(ws + ((size_t)128 << 20));// pass-1 scores fp32 (128M)
    float* P1   = (float*)ws;                       // pass-2 L1 partials 4x32M (128M)
    us*    H1g0 = (us*)(ws + ((size_t)128 << 20));  // pass-2 h1 hi [CAPF,2Q] (16M)
    us*    H1g1 = (us*)(ws + ((size_t)144 << 20));  // pass-2 h1 lo (16M)
    us*    H2g0 = (us*)(ws + ((size_t)160 << 20));  // pass-2 h2 hi [CAPF,Q] (8M)
    us*    H2g1 = (us*)(ws + ((size_t)168 << 20));  // pass-2 h2 lo (8M)
    float* SCg  = (float*)(ws + ((size_t)176 << 20));// pass-2 scores [CAPF,Q] (16M)
    us*    MASKB= (us*)(ws + ((size_t)192 << 20));  // mask bf16 [B,Q] (64M)
    int* KV     = (int*)(ws + ((size_t)256 << 20));
    int* FLAGS  = KV + B_;
    int* CNT    = FLAGS + B_;
    int* CNT2   = CNT + 1;
    int* FLAGS2 = CNT2 + 1;
    // ---- d_out map (scratch until final projection) ----
    us*    Xf   = (us*)dob;                         // x fp16 [B,Q] (64M)
    us*    H2f  = (us*)(dob + ((size_t)64 << 20));  // pass-1 h2 fp16 (64M)
    us*    Xg0  = (us*)dob;                         // gathered x hi (16M)
    us*    Xg1  = (us*)(dob + ((size_t)32 << 20));  // gathered x lo (16M)
    float* P23  = (float*)(dob + ((size_t)64 << 20));// pass-2 L2/L3 partials 4x16M (64M)
    float* H1F  = (float*)dob;                      // fp64-chain h1 [CAPF2,2Q] (8M)
    float* H2F  = (float*)(dob + ((size_t)8 << 20));
    float* SCF  = (float*)(dob + ((size_t)12 << 20));
    // ---- weight planes (fp16 first, overwritten by bf16 splits) ----
    char* WP = ws + ((size_t)256 << 20) + ((size_t)512 << 10);
    us* W1h = (us*)WP;                       us* W1f = (us*)WP;
    us* W1l = W1h + (size_t)2 * Q_ * Q_;
    us* W2h = W1l + (size_t)2 * Q_ * Q_;     us* W2f = W1l;   // overlaps (dead by then)
    us* W2l = W2h + (size_t)2 * Q_ * Q_;
    us* W3h = W2l + (size_t)2 * Q_ * Q_;     us* W3f = W2h;   // overlaps (dead by then)
    us* W3l = W3h + (size_t)Q_ * Q_;
    us* Wch = W3l + (size_t)Q_ * Q_;
    const size_t NEEDED = ((size_t)256 << 20) + ((size_t)512 << 10) + ((size_t)22 << 20);

    const size_t PS1 = (size_t)CAPF * 2 * Q_;   // partial stride (floats)
    const size_t PS2 = (size_t)CAPF * Q_;

    hipMemsetAsync(CNT, 0, 2 * sizeof(int), stream);
    dim3 blk(256);

    if (ws_size >= NEEDED) {
        // --- pass-1: fp16 single-pass selector ---
        cvt_plane_h<<<dim3(2048), blk, 0, stream>>>(x,  Xf,  B_ * Q_ / 8);
        cvt_plane_h<<<dim3(512),  blk, 0, stream>>>(W1, W1f, 2 * Q_ * Q_ / 8);
        cvt_plane_h<<<dim3(512),  blk, 0, stream>>>(W2, W2f, 2 * Q_ * Q_ / 8);
        cvt_plane_h<<<dim3(512),  blk, 0, stream>>>(W3, W3f, Q_ * Q_ / 8);
        gemm4r<1, Q_,     2, true,  true ><<<dim3(1024), dim3(512), 0, stream>>>(
            Xf,  nullptr, W1f, nullptr, H1f, nullptr, 2 * Q_);
        gemm4r<1, 2 * Q_, 2, true,  true ><<<dim3(512),  dim3(512), 0, stream>>>(
            H1f, nullptr, W2f, nullptr, H2f, nullptr, Q_);
        gemm4r<1, Q_,     0, false, true ><<<dim3(512),  dim3(512), 0, stream>>>(
            H2f, nullptr, W3f, nullptr, SC,  nullptr, Q_);
        row_argmax_flag<<<dim3(B_ / 4), blk, 0, stream>>>(SC, KV, FLAGS, CNT, 0.01f);
        // --- pass-2: bf16 3-pass split-K=4 on gathered flagged rows ---
        split_planes_k<<<dim3(512), blk, 0, stream>>>(W1, W1h, W1l, 2 * Q_ * Q_ / 8);
        split_planes_k<<<dim3(512), blk, 0, stream>>>(W2, W2h, W2l, 2 * Q_ * Q_ / 8);
        split_planes_k<<<dim3(512), blk, 0, stream>>>(W3, W3h, W3l, Q_ * Q_ / 8);
        cvt_plane_k   <<<dim3(512), blk, 0, stream>>>(Wc, Wch, E_ * Q_ / 8);
        gather_split<<<dim3(2048), blk, 0, stream>>>(x, FLAGS, CNT, Xg0, Xg1);
        gemm_sp<3, 4><<<dim3((CAPF / 128) * (2 * Q_ / 128), 4), blk, 0, stream>>>(
            Xg0,  Xg1,  W1h, W1l, P1,  PS1, 2 * Q_, Q_, CNT);
        finalize_k<4, 1><<<dim3(2048), blk, 0, stream>>>(P1,  PS1, H1g0, H1g1, nullptr, CNT, 2 * Q_);
        gemm_sp<3, 4><<<dim3((CAPF / 128) * (Q_ / 128), 4), blk, 0, stream>>>(
            H1g0, H1g1, W2h, W2l, P23, PS2, Q_, 2 * Q_, CNT);
        finalize_k<4, 1><<<dim3(2048), blk, 0, stream>>>(P23, PS2, H2g0, H2g1, nullptr, CNT, Q_);
        gemm_sp<3, 4><<<dim3((CAPF / 128) * (Q_ / 128), 4), blk, 0, stream>>>(
            H2g0, H2g1, W3h, W3l, P23, PS2, Q_, Q_, CNT);
        finalize_k<4, 0><<<dim3(2048), blk, 0, stream>>>(P23, PS2, nullptr, nullptr, SCg, CNT, Q_);
        g_argmax_flag2<<<dim3(1024), blk, 0, stream>>>(SCg, FLAGS, CNT, KV, FLAGS2, CNT2);
        // --- pass-3: fp64 exact rescore of pass-2 near-ties ---
        rescore_gemm<Q_,     true,  true ><<<dim3(4096), blk, 0, stream>>>(x,   W1, H1F, FLAGS2, CNT2, 2 * Q_, CAPF2);
        rescore_gemm<2 * Q_, false, true ><<<dim3(2048), blk, 0, stream>>>(H1F, W2, H2F, FLAGS2, CNT2, Q_,     CAPF2);
        rescore_gemm<Q_,     false, false><<<dim3(2048), blk, 0, stream>>>(H2F, W3, SCF, FLAGS2, CNT2, Q_,     CAPF2);
        rescore_argmax<<<dim3(64), blk, 0, stream>>>(SCF, FLAGS2, CNT2, KV, CAPF2);
        // --- mask + projection ---
        topk_mask_radix<<<dim3(B_ / 4), blk, 0, stream>>>(x, KV, MASKB);
        gemm4r<1, Q_, 0, false, false><<<dim3(512), dim3(512), 0, stream>>>(
            MASKB, nullptr, Wch, nullptr, out, nullptr, E_);
    } else {
        // fallback: round-4 path (in-kernel split, fp32 weights)
        us*    H1_0 = (us*)ws;
        us*    H1_1 = (us*)(ws + ((size_t)128 << 20));
        float* SCo  = (float*)ws;
        us*    MB   = (us*)(ws + ((size_t)128 << 20));
        us* H2_0 = (us*)d_out;
        us* H2_1 = (us*)d_out + (size_t)B_ * Q_;
        float* H1Fo = (float*)ws;
        float* H2Fo = (float*)(ws + ((size_t)128 << 20));
        float* SCFo = (float*)(ws + ((size_t)192 << 20));
        gemm3p<3, true,  true,  true ><<<dim3(2 * Q_ / 128, B_ / 128), blk, 0, stream>>>(
            x, nullptr, W1, H1_0, H1_1, B_, 2 * Q_, Q_);
        gemm3p<3, false, true,  true ><<<dim3(Q_ / 128, B_ / 128), blk, 0, stream>>>(
            H1_0, H1_1, W2, H2_0, H2_1, B_, Q_, 2 * Q_);
        gemm3p<3, false, false, false><<<dim3(Q_ / 128, B_ / 128), blk, 0, stream>>>(
            H2_0, H2_1, W3, SCo, nullptr, B_, Q_, Q_);
        row_argmax_flag<<<dim3(B_ / 4), blk, 0, stream>>>(SCo, KV, FLAGS, CNT, 1e-3f);
        rescore_gemm<Q_,     true,  true ><<<dim3(4096), blk, 0, stream>>>(x,    W1, H1Fo, FLAGS, CNT, 2 * Q_, CAPF);
        rescore_gemm<2 * Q_, false, true ><<<dim3(2048), blk, 0, stream>>>(H1Fo, W2, H2Fo, FLAGS, CNT, Q_,     CAPF);
        rescore_gemm<Q_,     false, false><<<dim3(2048), blk, 0, stream>>>(H2Fo, W3, SCFo, FLAGS, CNT, Q_,     CAPF);
        rescore_argmax<<<dim3(64), blk, 0, stream>>>(SCFo, FLAGS, CNT, KV, CAPF);
        topk_mask_radix<<<dim3(B_ / 4), blk, 0, stream>>>(x, KV, MB);
        gemm3p<1, false, false, false><<<dim3(E_ / 128, B_ / 128), blk, 0, stream>>>(
            MB, nullptr, Wc, out, nullptr, B_, E_, Q_);
    }
}

// Round 14
// 1063.951 us; speedup vs baseline: 1.2203x; 1.0151x over previous
//
#include <hip/hip_runtime.h>
#include <stdint.h>

#define B_  32768
#define Q_  1024
#define E_  1024
#define CAPF  4096    // stage-1 flag capacity (expected ~1900 at theta=0.008)
#define CAPF2 1024    // stage-2 flag capacity (rows refined by fp64)

typedef __attribute__((ext_vector_type(8))) short bf16x8;
typedef __attribute__((ext_vector_type(8))) _Float16 f16x8;
typedef __attribute__((ext_vector_type(8))) unsigned short u16x8;
typedef __attribute__((ext_vector_type(4))) float f32x4;
typedef unsigned short us;

__device__ __forceinline__ f32x4 MFMA16(bf16x8 a, bf16x8 b, f32x4 c) {
    return __builtin_amdgcn_mfma_f32_16x16x32_bf16(a, b, c, 0, 0, 0);
}
__device__ __forceinline__ f32x4 MFMA16H(bf16x8 a, bf16x8 b, f32x4 c) {
    return __builtin_amdgcn_mfma_f32_16x16x32_f16(
        __builtin_bit_cast(f16x8, a), __builtin_bit_cast(f16x8, b), c, 0, 0, 0);
}

__device__ __forceinline__ us f2bf(float v) {   // RNE fp32->bf16
    unsigned u = __float_as_uint(v);
    u += 0x7FFFu + ((u >> 16) & 1u);
    return (us)(u >> 16);
}
__device__ __forceinline__ float bf2f(us b) {
    return __uint_as_float(((unsigned)b) << 16);
}
__device__ __forceinline__ us f2h(float v) {    // RNE fp32->fp16 bits
    _Float16 h = (_Float16)v;
    return __builtin_bit_cast(unsigned short, h);
}

// ---------------- plane prep kernels (memory-bound, run once) ---------------
// fused fp32->fp16 conversion of 4 arrays (x, W1, W2, W3): one launch
__global__ __launch_bounds__(256)
void cvt4_h(const float* __restrict__ s0, us* __restrict__ d0, int e0,
            const float* __restrict__ s1, us* __restrict__ d1, int e1,
            const float* __restrict__ s2, us* __restrict__ d2, int e2,
            const float* __restrict__ s3, us* __restrict__ d3, int e3) {
    int i = blockIdx.x * 256 + threadIdx.x;
    const int stride = gridDim.x * 256;
    for (; i < e3; i += stride) {
        const float* s; us* d; int j;
        if (i < e0)      { s = s0; d = d0; j = i; }
        else if (i < e1) { s = s1; d = d1; j = i - e0; }
        else if (i < e2) { s = s2; d = d2; j = i - e1; }
        else             { s = s3; d = d3; j = i - e2; }
        float4 a = ((const float4*)s)[j * 2];
        float4 b = ((const float4*)s)[j * 2 + 1];
        float f[8] = {a.x, a.y, a.z, a.w, b.x, b.y, b.z, b.w};
        u16x8 h;
#pragma unroll
        for (int k = 0; k < 8; ++k) h[k] = f2h(f[k]);
        ((u16x8*)d)[j] = h;
    }
}

// fused bf16 hi/lo split of 3 weight arrays: one launch
__global__ __launch_bounds__(256)
void split3_k(const float* __restrict__ s0, us* __restrict__ h0, us* __restrict__ l0, int e0,
              const float* __restrict__ s1, us* __restrict__ h1, us* __restrict__ l1, int e1,
              const float* __restrict__ s2, us* __restrict__ h2, us* __restrict__ l2, int e2) {
    int i = blockIdx.x * 256 + threadIdx.x;
    const int stride = gridDim.x * 256;
    for (; i < e2; i += stride) {
        const float* s; us *dh, *dl; int j;
        if (i < e0)      { s = s0; dh = h0; dl = l0; j = i; }
        else if (i < e1) { s = s1; dh = h1; dl = l1; j = i - e0; }
        else             { s = s2; dh = h2; dl = l2; j = i - e1; }
        float4 a = ((const float4*)s)[j * 2];
        float4 b = ((const float4*)s)[j * 2 + 1];
        float f[8] = {a.x, a.y, a.z, a.w, b.x, b.y, b.z, b.w};
        u16x8 h, l;
#pragma unroll
        for (int k = 0; k < 8; ++k) {
            us c0 = f2bf(f[k]);
            h[k] = c0;
            l[k] = f2bf(f[k] - bf2f(c0));   // exact residual (Sterbenz)
        }
        ((u16x8*)dh)[j] = h;
        ((u16x8*)dl)[j] = l;
    }
}

__global__ __launch_bounds__(256)
void cvt_plane_k(const float* __restrict__ in, us* __restrict__ hi, int n8) {
    int i = blockIdx.x * 256 + threadIdx.x;
    const int stride = gridDim.x * 256;
    for (; i < n8; i += stride) {
        float4 a = ((const float4*)in)[i * 2];
        float4 b = ((const float4*)in)[i * 2 + 1];
        float f[8] = {a.x, a.y, a.z, a.w, b.x, b.y, b.z, b.w};
        u16x8 h;
#pragma unroll
        for (int j = 0; j < 8; ++j) h[j] = f2bf(f[j]);
        ((u16x8*)hi)[i] = h;
    }
}

// gather flagged rows of fp32 x and split into bf16 hi/lo planes [CAPF][Q]
__global__ __launch_bounds__(256)
void gather_split(const float* __restrict__ X, const int* __restrict__ flags,
                  const int* __restrict__ cnt, us* __restrict__ G0,
                  us* __restrict__ G1) {
    const int n = min(*cnt, CAPF);
    for (int it = blockIdx.x; it < n; it += gridDim.x) {
        int row = flags[it];
        if ((unsigned)row >= B_) row = 0;            // replay-safety clamp
        float4 v = ((const float4*)(X + (size_t)row * Q_))[threadIdx.x];
        float f[4] = {v.x, v.y, v.z, v.w};
        us h[4], l[4];
#pragma unroll
        for (int j = 0; j < 4; ++j) {
            h[j] = f2bf(f[j]);
            l[j] = f2bf(f[j] - bf2f(h[j]));
        }
        *(uint2*)&G0[(size_t)it * Q_ + threadIdx.x * 4] = *(uint2*)h;
        *(uint2*)&G1[(size_t)it * Q_ + threadIdx.x * 4] = *(uint2*)l;
    }
}

// sum SPLITS fp32 partials; MODE 0: fp32 out; MODE 1: relu + bf16 hi/lo planes
template<int SPLITS, int MODE>
__global__ __launch_bounds__(256)
void finalize_k(const float* __restrict__ P, size_t pstride,
                us* __restrict__ o0, us* __restrict__ o1,
                float* __restrict__ of, const int* __restrict__ cnt, int N) {
    const int n = min(*cnt, CAPF);
    const int total4 = n * (N >> 2);
    int i = blockIdx.x * 256 + threadIdx.x;
    const int stride = gridDim.x * 256;
    for (; i < total4; i += stride) {
        float4 s = ((const float4*)P)[i];
#pragma unroll
        for (int sp = 1; sp < SPLITS; ++sp) {
            float4 p = *(const float4*)(P + (size_t)sp * pstride + (size_t)i * 4);
            s.x += p.x; s.y += p.y; s.z += p.z; s.w += p.w;
        }
        if constexpr (MODE == 0) {
            ((float4*)of)[i] = s;
        } else {
            float f[4] = {fmaxf(s.x, 0.f), fmaxf(s.y, 0.f),
                          fmaxf(s.z, 0.f), fmaxf(s.w, 0.f)};
            us h[4], l[4];
#pragma unroll
            for (int j = 0; j < 4; ++j) {
                h[j] = f2bf(f[j]);
                l[j] = f2bf(f[j] - bf2f(h[j]));
            }
            *(uint2*)&o0[(size_t)i * 4] = *(uint2*)h;
            *(uint2*)&o1[(size_t)i * 4] = *(uint2*)l;
        }
    }
}

// ============================================================================
// 256x256-tile GEMM (round-8 verified core). 8 waves (2Mx4N), BK=32, 4-slot
// whole-tile LDS ring (128 KiB), safe deep pipeline:
//   half-step: RD(frags t+1) || stage(t+4, clamped) || MFMA(t)
//              -> lgkmcnt(0) -> vmcnt(8) -> s_barrier
// NSEG=3: acc = A0B0 + A0B1 + A1B0 over K'=3K (fp32-grade split-bf16).
// EMIT: 0=fp32, 1=bf16 hi/lo pair, 2=fp16. FP16: f16 MFMA.
// ============================================================================
#define LGKM0() asm volatile("s_waitcnt lgkmcnt(0)" ::: "memory")
#define VMC8()  asm volatile("s_waitcnt vmcnt(8)" ::: "memory")
#define BAR()   __builtin_amdgcn_s_barrier()
#define RD_AB(Aarr, Barr, slot) { \
    const us* _la = &LA[(slot) * 8192]; const us* _lb = &LB[(slot) * 8192]; \
    _Pragma("unroll") for (int mf = 0; mf < 8; ++mf) Aarr[mf] = *(const bf16x8*)&_la[ago[mf]]; \
    _Pragma("unroll") for (int nf = 0; nf < 4; ++nf) Barr[nf] = *(const bf16x8*)&_lb[bgo[nf]]; }
#define CLX(AF, BF) { __builtin_amdgcn_s_setprio(1); \
    _Pragma("unroll") for (int mf = 0; mf < 8; ++mf) { \
        _Pragma("unroll") for (int nf = 0; nf < 4; ++nf) { \
            if constexpr (FP16) acc[mf][nf] = MFMA16H(AF[mf], BF[nf], acc[mf][nf]); \
            else               acc[mf][nf] = MFMA16 (AF[mf], BF[nf], acc[mf][nf]); } } \
    __builtin_amdgcn_s_setprio(0); }

template<int NSEG, int K, int EMIT, bool RELU, bool FP16>
__global__ __launch_bounds__(512, 2)
void gemm4r(const us* __restrict__ A0p, const us* __restrict__ A1p,
            const us* __restrict__ B0p, const us* __restrict__ B1p,
            void* __restrict__ Cp0, void* __restrict__ Cp1, int N) {
    constexpr int TPS = K / 32;
    constexpr int NT  = NSEG * TPS;
    static_assert(NT % 2 == 0 && NT >= 4, "shape");
    __shared__ __align__(16) us LA[4 * 8192];
    __shared__ __align__(16) us LB[4 * 8192];

    const int t = threadIdx.x;
    const int wv = t >> 6, lane = t & 63;
    const int lanelo = lane & 15, kq = lane >> 4;
    const int wm = wv >> 2, wn = wv & 3;

    const int q8 = gridDim.x >> 3;       // grid % 8 == 0 (T1 bijective swizzle)
    const int logical = ((int)blockIdx.x & 7) * q8 + ((int)blockIdx.x >> 3);
    const int gx = N >> 8;
    const int m0 = (logical / gx) * 256, n0 = (logical % gx) * 256;

    int soff[2], ldst[2];
#pragma unroll
    for (int i = 0; i < 2; ++i) {
        int s = i * 512 + t;
        int row = s >> 2, c = s & 3;
        soff[i] = row * K + (c ^ ((row >> 1) & 3)) * 8;
        ldst[i] = (i * 512 + wv * 64) * 8;
    }
    int ago[8], bgo[4];
#pragma unroll
    for (int mf = 0; mf < 8; ++mf) {
        int row = wm * 128 + mf * 16 + lanelo;
        ago[mf] = (row * 4 + (kq ^ ((row >> 1) & 3))) * 8;
    }
#pragma unroll
    for (int nf = 0; nf < 4; ++nf) {
        int row = wn * 64 + nf * 16 + lanelo;
        bgo[nf] = (row * 4 + (kq ^ ((row >> 1) & 3))) * 8;
    }

    auto stage = [&](int tv) {
        int slot = tv & 3;
        int seg = tv / TPS;
        int kb  = (tv - seg * TPS) * 32;
        const us* Ap = (NSEG == 1 || seg < 2) ? A0p : A1p;
        const us* Bp = (NSEG == 3 && seg == 1) ? B1p : B0p;
        const us* Abase = Ap + (size_t)m0 * K + kb;
        const us* Bbase = Bp + (size_t)n0 * K + kb;
        us* dA = &LA[slot * 8192];
        us* dB = &LB[slot * 8192];
#pragma unroll
        for (int i = 0; i < 2; ++i) {
            __builtin_amdgcn_global_load_lds(
                (const __attribute__((address_space(1))) void*)(Abase + soff[i]),
                (__attribute__((address_space(3))) void*)(dA + ldst[i]), 16, 0, 0);
            __builtin_amdgcn_global_load_lds(
                (const __attribute__((address_space(1))) void*)(Bbase + soff[i]),
                (__attribute__((address_space(3))) void*)(dB + ldst[i]), 16, 0, 0);
        }
    };

    f32x4 acc[8][4];
#pragma unroll
    for (int i = 0; i < 8; ++i)
#pragma unroll
        for (int j = 0; j < 4; ++j) acc[i][j] = (f32x4){0.f, 0.f, 0.f, 0.f};

    bf16x8 aE[8], bE[4], aO[8], bO[4];

    stage(0); stage(1); stage(2);
    VMC8();  BAR();
    RD_AB(aE, bE, 0);
    stage(3);
    LGKM0(); VMC8(); BAR();

    for (int tt = 0; tt < NT; tt += 2) {
        RD_AB(aO, bO, (tt + 1) & 3);
        { int tv = tt + 4; if (tv > NT - 1) tv = NT - 1; stage(tv); }
        CLX(aE, bE);
        LGKM0(); VMC8(); BAR();
        { int tn = (tt + 2 < NT) ? (tt + 2) : (NT - 1);
          RD_AB(aE, bE, tn & 3); }
        { int tv = tt + 5; if (tv > NT - 1) tv = NT - 1; stage(tv); }
        CLX(aO, bO);
        LGKM0(); VMC8(); BAR();
    }

    // epilogue: C/D layout col=lane&15, row=(lane>>4)*4+reg (m89/m91)
#pragma unroll
    for (int mf = 0; mf < 8; ++mf)
#pragma unroll
        for (int nf = 0; nf < 4; ++nf)
#pragma unroll
            for (int r = 0; r < 4; ++r) {
                int row = m0 + wm * 128 + mf * 16 + kq * 4 + r;
                int col = n0 + wn * 64 + nf * 16 + lanelo;
                float v = acc[mf][nf][r];
                if constexpr (RELU) v = fmaxf(v, 0.f);
                if constexpr (EMIT == 1) {
                    us c0 = f2bf(v);
                    ((us*)Cp0)[(size_t)row * N + col] = c0;
                    ((us*)Cp1)[(size_t)row * N + col] = f2bf(v - bf2f(c0));
                } else if constexpr (EMIT == 2) {
                    ((us*)Cp0)[(size_t)row * N + col] = f2h(v);
                } else {
                    ((float*)Cp0)[(size_t)row * N + col] = v;
                }
            }
}

// ============================================================================
// 128x128-tile split-K all-plane GEMM for the gathered pass. grid.y = split.
// Split s computes real-K [s*K/S,(s+1)*K/S) of all NSEG segments into fp32
// partial P + s*pstride. DYN early-exit on m-tiles beyond ceil(n/128).
// Verified swizzle pair ((row>>1)&3) both sides -> 0 bank conflicts.
// ============================================================================
template<int NPASS, int SPLITS>
__global__ __launch_bounds__(256, 4)
void gemm_sp(const us* __restrict__ A0, const us* __restrict__ A1,
             const us* __restrict__ B0, const us* __restrict__ B1,
             float* __restrict__ P, size_t pstride,
             int N, int K, const int* __restrict__ ncnt) {
    __shared__ __align__(16) us A0s[128 * 32];
    __shared__ __align__(16) us B0s[128 * 32];

    const int t = threadIdx.x;
    const int wave = t >> 6, lane = t & 63;
    const int lanelo = lane & 15, kq = lane >> 4;
    const int wm = wave >> 1, wn = wave & 1;
    const int q8 = gridDim.x >> 3;                 // grid.x divisible by 8
    const int logical = ((int)blockIdx.x & 7) * q8 + ((int)blockIdx.x >> 3);
    const int gx = N >> 7;
    const int m0 = (logical / gx) * 128, n0 = (logical % gx) * 128;
    const int split = blockIdx.y;

    int nn = *ncnt; if (nn > CAPF) nn = CAPF;
    if (m0 >= ((nn + 127) & ~127)) return;

    const int Ks = K / SPLITS;
    const int kbase = split * Ks;
    const int tps = Ks >> 5;

    f32x4 acc[4][4];
#pragma unroll
    for (int i = 0; i < 4; ++i)
#pragma unroll
        for (int j = 0; j < 4; ++j) acc[i][j] = (f32x4){0.f, 0.f, 0.f, 0.f};

    for (int vt = 0; vt < NPASS * tps; ++vt) {
        const int seg = vt / tps;
        const int kt  = kbase + (vt - seg * tps) * 32;
        const us* Ap = (NPASS == 1 || seg < 2) ? A0 : A1;
        const us* Bp = (NPASS == 3 && seg == 1) ? B1 : B0;
        __syncthreads();
#pragma unroll
        for (int g = 0; g < 2; ++g) {
            int c = (g * 4 + wave) * 64 + lane;
            int row = c >> 2;
            int koff = (c & 3) ^ ((row >> 1) & 3);   // pre-swizzled source
            size_t offa = (size_t)(m0 + row) * K + kt + koff * 8;
            size_t offb = (size_t)(n0 + row) * K + kt + koff * 8;
            int dst = (g * 4 + wave) * 512;
            __builtin_amdgcn_global_load_lds(
                (const __attribute__((address_space(1))) void*)(Ap + offa),
                (__attribute__((address_space(3))) void*)&A0s[dst], 16, 0, 0);
            __builtin_amdgcn_global_load_lds(
                (const __attribute__((address_space(1))) void*)(Bp + offb),
                (__attribute__((address_space(3))) void*)&B0s[dst], 16, 0, 0);
        }
        __syncthreads();

        bf16x8 a0[4];
#pragma unroll
        for (int mf = 0; mf < 4; ++mf) {
            int ar = wm * 64 + mf * 16 + lanelo;
            int ac = ar * 4 + (kq ^ ((ar >> 1) & 3));
            a0[mf] = *(const bf16x8*)&A0s[ac * 8];
        }
#pragma unroll
        for (int nf = 0; nf < 4; ++nf) {
            int br = wn * 64 + nf * 16 + lanelo;
            int bc = br * 4 + (kq ^ ((br >> 1) & 3));
            bf16x8 vb0 = *(const bf16x8*)&B0s[bc * 8];
#pragma unroll
            for (int mf = 0; mf < 4; ++mf) acc[mf][nf] = MFMA16(a0[mf], vb0, acc[mf][nf]);
        }
    }

    float* Pd = P + (size_t)split * pstride;
#pragma unroll
    for (int mf = 0; mf < 4; ++mf)
#pragma unroll
        for (int nf = 0; nf < 4; ++nf)
#pragma unroll
            for (int r = 0; r < 4; ++r) {
                int row = m0 + wm * 64 + mf * 16 + kq * 4 + r;
                int col = n0 + wn * 64 + nf * 16 + lanelo;
                Pd[(size_t)row * N + col] = acc[mf][nf][r];
            }
}

// ---------------- fallback GEMM (round-4 path, in-kernel split) -------------
__device__ __forceinline__ int chunk_of(int row, int koff) {
    return row * 4 + (koff ^ (row & 3));
}

template<int NPASS>
__device__ __forceinline__ void split_store(us* S0, us* S1,
                                            int rowX, int koffX, float4 a, float4 b) {
    int ch = chunk_of(rowX, koffX);
    float f[8] = {a.x, a.y, a.z, a.w, b.x, b.y, b.z, b.w};
    bf16x8 lo, hi;
#pragma unroll
    for (int j = 0; j < 8; ++j) {
        us c0 = f2bf(f[j]);
        lo[j] = (short)c0;
        hi[j] = (short)f2bf(f[j] - bf2f(c0));
    }
    *(bf16x8*)&S0[ch * 8] = lo;
    if constexpr (NPASS == 3) *(bf16x8*)&S1[ch * 8] = hi;
}

template<int NPASS, bool AF32, bool RELU, bool EMITP>
__global__ __launch_bounds__(256, 2)
void gemm3p(const void* __restrict__ Ap0, const void* __restrict__ Ap1,
            const float* __restrict__ Wf,
            void* __restrict__ Cp0, void* __restrict__ Cp1,
            int M, int N, int K) {
    __shared__ __align__(16) us A0s[128 * 32];
    __shared__ __align__(16) us B0s[128 * 32];
    __shared__ __align__(16) us A1s[(NPASS == 3) ? 128 * 32 : 8];
    __shared__ __align__(16) us B1s[(NPASS == 3) ? 128 * 32 : 8];

    const int t = threadIdx.x;
    const int wave = t >> 6, lane = t & 63;
    const int lanelo = lane & 15, kq = lane >> 4;
    const int wm = wave >> 1, wn = wave & 1;
    const int m0 = blockIdx.y * 128, n0 = blockIdx.x * 128;
    const int brow = t >> 1, bhalf = t & 1;

    f32x4 acc[4][4];
#pragma unroll
    for (int i = 0; i < 4; ++i)
#pragma unroll
        for (int j = 0; j < 4; ++j) acc[i][j] = (f32x4){0.f, 0.f, 0.f, 0.f};

    for (int kt = 0; kt < K; kt += 32) {
        __syncthreads();
        const float* wp = Wf + (size_t)(n0 + brow) * K + kt + bhalf * 16;
        float4 v0 = *(const float4*)(wp + 0);
        float4 v1 = *(const float4*)(wp + 4);
        float4 v2 = *(const float4*)(wp + 8);
        float4 v3 = *(const float4*)(wp + 12);
        if constexpr (AF32) {
            const float* ap = (const float*)Ap0 + (size_t)(m0 + brow) * K + kt + bhalf * 16;
            float4 u0 = *(const float4*)(ap + 0);
            float4 u1 = *(const float4*)(ap + 4);
            float4 u2 = *(const float4*)(ap + 8);
            float4 u3 = *(const float4*)(ap + 12);
            split_store<NPASS>(A0s, A1s, brow, bhalf * 2 + 0, u0, u1);
            split_store<NPASS>(A0s, A1s, brow, bhalf * 2 + 1, u2, u3);
        } else {
#pragma unroll
            for (int g = 0; g < 2; ++g) {
                int c = (g * 4 + wave) * 64 + lane;
                int row = c >> 2;
                int koff = (c & 3) ^ (row & 3);
                const us* s0 = (const us*)Ap0 + (size_t)(m0 + row) * K + kt + koff * 8;
                __builtin_amdgcn_global_load_lds(
                    (const __attribute__((address_space(1))) void*)s0,
                    (__attribute__((address_space(3))) void*)&A0s[(size_t)(g * 4 + wave) * 512],
                    16, 0, 0);
                if constexpr (NPASS == 3) {
                    const us* s1 = (const us*)Ap1 + (size_t)(m0 + row) * K + kt + koff * 8;
                    __builtin_amdgcn_global_load_lds(
                        (const __attribute__((address_space(1))) void*)s1,
                        (__attribute__((address_space(3))) void*)&A1s[(size_t)(g * 4 + wave) * 512],
                        16, 0, 0);
                }
            }
        }
        split_store<NPASS>(B0s, B1s, brow, bhalf * 2 + 0, v0, v1);
        split_store<NPASS>(B0s, B1s, brow, bhalf * 2 + 1, v2, v3);
        __syncthreads();

        bf16x8 a0[4], a1[4];
#pragma unroll
        for (int mf = 0; mf < 4; ++mf) {
            int ar = wm * 64 + mf * 16 + lanelo;
            int ac = chunk_of(ar, kq);
            a0[mf] = *(const bf16x8*)&A0s[ac * 8];
            if constexpr (NPASS == 3) a1[mf] = *(const bf16x8*)&A1s[ac * 8];
        }
#pragma unroll
        for (int nf = 0; nf < 4; ++nf) {
            int br = wn * 64 + nf * 16 + lanelo;
            int bc = chunk_of(br, kq);
            bf16x8 vb0 = *(const bf16x8*)&B0s[bc * 8];
#pragma unroll
            for (int mf = 0; mf < 4; ++mf) acc[mf][nf] = MFMA16(a0[mf], vb0, acc[mf][nf]);
            if constexpr (NPASS == 3) {
                bf16x8 vb1 = *(const bf16x8*)&B1s[bc * 8];
#pragma unroll
                for (int mf = 0; mf < 4; ++mf) acc[mf][nf] = MFMA16(a0[mf], vb1, acc[mf][nf]);
#pragma unroll
                for (int mf = 0; mf < 4; ++mf) acc[mf][nf] = MFMA16(a1[mf], vb0, acc[mf][nf]);
            }
        }
    }

#pragma unroll
    for (int mf = 0; mf < 4; ++mf)
#pragma unroll
        for (int nf = 0; nf < 4; ++nf)
#pragma unroll
            for (int r = 0; r < 4; ++r) {
                int row = m0 + wm * 64 + mf * 16 + kq * 4 + r;
                int col = n0 + wn * 64 + nf * 16 + lanelo;
                float v = acc[mf][nf][r];
                if constexpr (RELU) v = fmaxf(v, 0.f);
                if constexpr (EMITP) {
                    us c0 = f2bf(v);
                    ((us*)Cp0)[(size_t)row * N + col] = c0;
                    ((us*)Cp1)[(size_t)row * N + col] = f2bf(v - bf2f(c0));
                } else {
                    ((float*)Cp0)[(size_t)row * N + col] = v;
                }
            }
}

// k[row] = argmax+1 (first occurrence); flag rows whose top-2 gap < theta
__global__ __launch_bounds__(256)
void row_argmax_flag(const float* __restrict__ S, int* __restrict__ KV,
                     int* __restrict__ flags, int* __restrict__ cnt, float theta) {
    int row = blockIdx.x * 4 + (threadIdx.x >> 6);
    int lane = threadIdx.x & 63;
    const float* s = S + (size_t)row * Q_;
    float b1 = -3.4e38f, b2 = -3.4e38f; int i1 = 0;
    for (int j = lane; j < Q_; j += 64) {
        float v = s[j];
        if (v > b1) { b2 = b1; b1 = v; i1 = j; }
        else if (v > b2) b2 = v;
    }
#pragma unroll
    for (int m = 1; m < 64; m <<= 1) {
        float o1 = __shfl_xor(b1, m);
        int   oi = __shfl_xor(i1, m);
        float o2 = __shfl_xor(b2, m);
        if (o1 > b1 || (o1 == b1 && oi < i1)) {
            b2 = fmaxf(b1, o2);
            b1 = o1; i1 = oi;
        } else {
            b2 = fmaxf(b2, o1);
        }
    }
    if (lane == 0) {
        KV[row] = i1 + 1;
        if (b1 - b2 < theta) {
            int p = atomicAdd(cnt, 1);
            if (p < CAPF) flags[p] = row;
        }
    }
}

// argmax over gathered (pass-2) scores: scatter k, flag near-ties for fp64
__global__ __launch_bounds__(256)
void g_argmax_flag2(const float* __restrict__ SCg, const int* __restrict__ flags,
                    const int* __restrict__ cnt, int* __restrict__ KV,
                    int* __restrict__ flags2, int* __restrict__ cnt2) {
    const int lane = threadIdx.x & 63, wv = threadIdx.x >> 6;
    const int n = min(*cnt, CAPF);
    for (int it = blockIdx.x * 4 + wv; it < n; it += gridDim.x * 4) {
        const float* s = SCg + (size_t)it * Q_;
        float b1 = -3.4e38f, b2 = -3.4e38f; int i1 = 0;
        for (int j = lane; j < Q_; j += 64) {
            float v = s[j];
            if (v > b1) { b2 = b1; b1 = v; i1 = j; }
            else if (v > b2) b2 = v;
        }
#pragma unroll
        for (int m = 1; m < 64; m <<= 1) {
            float o1 = __shfl_xor(b1, m);
            int   oi = __shfl_xor(i1, m);
            float o2 = __shfl_xor(b2, m);
            if (o1 > b1 || (o1 == b1 && oi < i1)) {
                b2 = fmaxf(b1, o2);
                b1 = o1; i1 = oi;
            } else {
                b2 = fmaxf(b2, o1);
            }
        }
        if (lane == 0) {
            int r = flags[it];
            if ((unsigned)r < B_) {
                KV[r] = i1 + 1;
                if (b1 - b2 < 1e-3f) {
                    int p = atomicAdd(cnt2, 1);
                    if (p < CAPF2) flags2[p] = r;
                }
            }
        }
    }
}

// ---- parallel coalesced rescore (fp64): K compile-time, float4 loads ----
template<int K, bool IN_BY_FLAG, bool RELU>
__global__ __launch_bounds__(256)
void rescore_gemm(const float* __restrict__ IN, const float* __restrict__ W,
                  float* __restrict__ OUT, const int* __restrict__ flags,
                  const int* __restrict__ cnt, int N, int cap) {
    __shared__ float xr[K];
    const int t = threadIdx.x, lane = t & 63, wv = t >> 6;
    const int n = min(*cnt, cap);
    const int chunks = N >> 4;
    for (int w = blockIdx.x; w < n * chunks; w += gridDim.x) {
        const int it = w / chunks, ch = w - it * chunks;
        int srow = IN_BY_FLAG ? flags[it] : it;
        if (IN_BY_FLAG && (unsigned)srow >= B_) srow = 0;   // replay-safety clamp
        const float* rp = IN + (size_t)srow * K;
        __syncthreads();
#pragma unroll
        for (int p = t; p < K / 4; p += 256)
            ((float4*)xr)[p] = ((const float4*)rp)[p];
        __syncthreads();
#pragma unroll
        for (int jj = 0; jj < 4; ++jj) {
            const int col = ch * 16 + wv * 4 + jj;
            const float* wr = W + (size_t)col * K;
            double a0 = 0.0, a1 = 0.0;
#pragma unroll
            for (int i = 0; i < K / 256; ++i) {
                const int k = i * 256 + lane * 4;
                float4 w4 = *(const float4*)(wr + k);
                float4 x4 = *(const float4*)(xr + k);
                a0 += (double)x4.x * w4.x + (double)x4.y * w4.y;
                a1 += (double)x4.z * w4.z + (double)x4.w * w4.w;
            }
            double a = a0 + a1;
#pragma unroll
            for (int m = 1; m < 64; m <<= 1) a += __shfl_xor(a, m);
            if (lane == 0) {
                float v = (float)a;
                if (RELU) v = fmaxf(v, 0.f);
                OUT[(size_t)it * N + col] = v;
            }
        }
    }
}

// final exact argmax over fp64-rescored rows, first-occurrence tie-break
__global__ __launch_bounds__(256)
void rescore_argmax(const float* __restrict__ SCF, const int* __restrict__ flags,
                    const int* __restrict__ cnt, int* __restrict__ KV, int cap) {
    const int lane = threadIdx.x & 63, wv = threadIdx.x >> 6;
    const int n = min(*cnt, cap);
    for (int it = blockIdx.x * 4 + wv; it < n; it += gridDim.x * 4) {
        const float* s = SCF + (size_t)it * Q_;
        float best = -3.4e38f; int bi = 0;
        for (int j = lane; j < Q_; j += 64) {
            float v = s[j];
            if (v > best) { best = v; bi = j; }
        }
#pragma unroll
        for (int m = 1; m < 64; m <<= 1) {
            float ov = __shfl_xor(best, m); int oi = __shfl_xor(bi, m);
            if (ov > best || (ov == best && oi < bi)) { best = ov; bi = oi; }
        }
        if (lane == 0) {
            int r = flags[it];
            if ((unsigned)r < B_) KV[r] = bi + 1;
        }
    }
}

// ---- stable top-k mask via in-register bit-descent radix select ----
__global__ __launch_bounds__(256)
void topk_mask_radix(const float* __restrict__ X, const int* __restrict__ KV,
                     us* __restrict__ Mout) {
    const int row  = blockIdx.x * 4 + (threadIdx.x >> 6);
    const int lane = threadIdx.x & 63;
    const float* x = X + (size_t)row * Q_;

    unsigned u[16];
#pragma unroll
    for (int j4 = 0; j4 < 4; ++j4) {
        float4 v = *(const float4*)(x + lane * 16 + j4 * 4);
        float f[4] = {v.x, v.y, v.z, v.w};
#pragma unroll
        for (int e = 0; e < 4; ++e) {
            unsigned fb = __float_as_uint(f[e]);
            u[j4 * 4 + e] = (fb & 0x80000000u) ? ~fb : (fb | 0x80000000u);
        }
    }
    const int k = KV[row];

    unsigned p = 0;
#pragma unroll
    for (int b = 31; b >= 0; --b) {
        unsigned q = p | (1u << b);
        int c = 0;
#pragma unroll
        for (int j = 0; j < 16; ++j) c += (u[j] >= q);
#pragma unroll
        for (int m = 1; m < 64; m <<= 1) c += __shfl_xor(c, m);
        if (c >= k) p = q;
    }

    int gt = 0, eqloc = 0;
#pragma unroll
    for (int j = 0; j < 16; ++j) { gt += (u[j] > p); eqloc += (u[j] == p); }
    int gtot = gt;
#pragma unroll
    for (int m = 1; m < 64; m <<= 1) gtot += __shfl_xor(gtot, m);
    int scan = eqloc;
#pragma unroll
    for (int d = 1; d < 64; d <<= 1) {
        int o = __shfl_up(scan, d);
        if (lane >= d) scan += o;
    }
    int run = scan - eqloc;
    const int quota = k - gtot;

    us m16[16];
#pragma unroll
    for (int j = 0; j < 16; ++j) {
        bool one;
        if (u[j] > p) one = true;
        else if (u[j] == p) { one = (run < quota); ++run; }
        else one = false;
        m16[j] = one ? (us)0x3F80 : (us)0;
    }
    u16x8* dst = (u16x8*)(Mout + (size_t)row * Q_ + lane * 16);
    dst[0] = *(u16x8*)&m16[0];
    dst[1] = *(u16x8*)&m16[8];
}

extern "C" void kernel_launch(void* const* d_in, const int* in_sizes, int n_in,
                              void* d_out, int out_size, void* d_ws, size_t ws_size,
                              hipStream_t stream) {
    const float* x  = (const float*)d_in[0];
    const float* W1 = (const float*)d_in[1];   // [2Q, Q]
    const float* W2 = (const float*)d_in[2];   // [Q, 2Q]
    const float* W3 = (const float*)d_in[3];   // [Q, Q]
    const float* Wc = (const float*)d_in[4];   // [E, Q]
    float* out = (float*)d_out;

    char* ws = (char*)d_ws;
    char* dob = (char*)d_out;
    // ---- ws map (fast path) ----
    us*    H1f  = (us*)ws;                          // pass-1 h1 fp16 [B,2Q] (128M)
    float* SC   = (float*)(ws + ((size_t)128 << 20));// pass-1 scores fp32 (128M)
    float* P1   = (float*)ws;                       // pass-2 L1 partials 4x32M (128M)
    us*    H1g0 = (us*)(ws + ((size_t)128 << 20));  // pass-2 h1 hi [CAPF,2Q] (16M)
    us*    H1g1 = (us*)(ws + ((size_t)144 << 20));  // pass-2 h1 lo (16M)
    us*    H2g0 = (us*)(ws + ((size_t)160 << 20));  // pass-2 h2 hi [CAPF,Q] (8M)
    us*    H2g1 = (us*)(ws + ((size_t)168 << 20));  // pass-2 h2 lo (8M)
    float* SCg  = (float*)(ws + ((size_t)176 << 20));// pass-2 scores [CAPF,Q] (16M)
    us*    MASKB= (us*)(ws + ((size_t)192 << 20));  // mask bf16 [B,Q] (64M)
    int* KV     = (int*)(ws + ((size_t)256 << 20));
    int* FLAGS  = KV + B_;
    int* CNT    = FLAGS + B_;
    int* CNT2   = CNT + 1;
    int* FLAGS2 = CNT2 + 1;
    // ---- d_out map (scratch until final projection) ----
    us*    Xf   = (us*)dob;                         // x fp16 [B,Q] (64M)
    us*    H2f  = (us*)(dob + ((size_t)64 << 20));  // pass-1 h2 fp16 (64M)
    us*    Xg0  = (us*)dob;                         // gathered x hi (16M)
    us*    Xg1  = (us*)(dob + ((size_t)32 << 20));  // gathered x lo (16M)
    float* P23  = (float*)(dob + ((size_t)64 << 20));// pass-2 L2/L3 partials 4x16M (64M)
    float* H1F  = (float*)dob;                      // fp64-chain h1 [CAPF2,2Q] (8M)
    float* H2F  = (float*)(dob + ((size_t)8 << 20));
    float* SCF  = (float*)(dob + ((size_t)12 << 20));
    // ---- weight planes (fp16 first, overwritten by bf16 splits) ----
    char* WP = ws + ((size_t)256 << 20) + ((size_t)512 << 10);
    us* W1h = (us*)WP;                       us* W1f = (us*)WP;
    us* W1l = W1h + (size_t)2 * Q_ * Q_;
    us* W2h = W1l + (size_t)2 * Q_ * Q_;     us* W2f = W1l;   // overlaps (dead by then)
    us* W2l = W2h + (size_t)2 * Q_ * Q_;
    us* W3h = W2l + (size_t)2 * Q_ * Q_;     us* W3f = W2h;   // overlaps (dead by then)
    us* W3l = W3h + (size_t)Q_ * Q_;
    us* Wch = W3l + (size_t)Q_ * Q_;
    const size_t NEEDED = ((size_t)256 << 20) + ((size_t)512 << 10) + ((size_t)22 << 20);

    const size_t PS1 = (size_t)CAPF * 2 * Q_;   // partial stride (floats)
    const size_t PS2 = (size_t)CAPF * Q_;

    hipMemsetAsync(CNT, 0, 2 * sizeof(int), stream);
    dim3 blk(256);

    if (ws_size >= NEEDED) {
        // --- pass-1: fp16 single-pass selector (fused prep: 1 launch) ---
        const int ex  = B_ * Q_ / 8;
        const int ew1 = ex + 2 * Q_ * Q_ / 8;
        const int ew2 = ew1 + 2 * Q_ * Q_ / 8;
        const int ew3 = ew2 + Q_ * Q_ / 8;
        cvt4_h<<<dim3(2048), blk, 0, stream>>>(x, Xf, ex, W1, W1f, ew1,
                                               W2, W2f, ew2, W3, W3f, ew3);
        gemm4r<1, Q_,     2, true,  true ><<<dim3(1024), dim3(512), 0, stream>>>(
            Xf,  nullptr, W1f, nullptr, H1f, nullptr, 2 * Q_);
        gemm4r<1, 2 * Q_, 2, true,  true ><<<dim3(512),  dim3(512), 0, stream>>>(
            H1f, nullptr, W2f, nullptr, H2f, nullptr, Q_);
        gemm4r<1, Q_,     0, false, true ><<<dim3(512),  dim3(512), 0, stream>>>(
            H2f, nullptr, W3f, nullptr, SC,  nullptr, Q_);
        // theta=0.008 = 7.3 sigma of the derived fp16 gap-error model (r14 pm)
        row_argmax_flag<<<dim3(B_ / 4), blk, 0, stream>>>(SC, KV, FLAGS, CNT, 0.008f);
        // --- pass-2: bf16 3-pass split-K=4 on gathered flagged rows ---
        const int es1 = 2 * Q_ * Q_ / 8;
        const int es2 = es1 + 2 * Q_ * Q_ / 8;
        const int es3 = es2 + Q_ * Q_ / 8;
        split3_k<<<dim3(1024), blk, 0, stream>>>(W1, W1h, W1l, es1,
                                                 W2, W2h, W2l, es2,
                                                 W3, W3h, W3l, es3);
        cvt_plane_k<<<dim3(512), blk, 0, stream>>>(Wc, Wch, E_ * Q_ / 8);
        gather_split<<<dim3(2048), blk, 0, stream>>>(x, FLAGS, CNT, Xg0, Xg1);
        gemm_sp<3, 4><<<dim3((CAPF / 128) * (2 * Q_ / 128), 4), blk, 0, stream>>>(
            Xg0,  Xg1,  W1h, W1l, P1,  PS1, 2 * Q_, Q_, CNT);
        finalize_k<4, 1><<<dim3(2048), blk, 0, stream>>>(P1,  PS1, H1g0, H1g1, nullptr, CNT, 2 * Q_);
        gemm_sp<3, 4><<<dim3((CAPF / 128) * (Q_ / 128), 4), blk, 0, stream>>>(
            H1g0, H1g1, W2h, W2l, P23, PS2, Q_, 2 * Q_, CNT);
        finalize_k<4, 1><<<dim3(2048), blk, 0, stream>>>(P23, PS2, H2g0, H2g1, nullptr, CNT, Q_);
        gemm_sp<3, 4><<<dim3((CAPF / 128) * (Q_ / 128), 4), blk, 0, stream>>>(
            H2g0, H2g1, W3h, W3l, P23, PS2, Q_, Q_, CNT);
        finalize_k<4, 0><<<dim3(2048), blk, 0, stream>>>(P23, PS2, nullptr, nullptr, SCg, CNT, Q_);
        g_argmax_flag2<<<dim3(1024), blk, 0, stream>>>(SCg, FLAGS, CNT, KV, FLAGS2, CNT2);
        // --- pass-3: fp64 exact rescore of pass-2 near-ties ---
        rescore_gemm<Q_,     true,  true ><<<dim3(4096), blk, 0, stream>>>(x,   W1, H1F, FLAGS2, CNT2, 2 * Q_, CAPF2);
        rescore_gemm<2 * Q_, false, true ><<<dim3(2048), blk, 0, stream>>>(H1F, W2, H2F, FLAGS2, CNT2, Q_,     CAPF2);
        rescore_gemm<Q_,     false, false><<<dim3(2048), blk, 0, stream>>>(H2F, W3, SCF, FLAGS2, CNT2, Q_,     CAPF2);
        rescore_argmax<<<dim3(64), blk, 0, stream>>>(SCF, FLAGS2, CNT2, KV, CAPF2);
        // --- mask + projection ---
        topk_mask_radix<<<dim3(B_ / 4), blk, 0, stream>>>(x, KV, MASKB);
        gemm4r<1, Q_, 0, false, false><<<dim3(512), dim3(512), 0, stream>>>(
            MASKB, nullptr, Wch, nullptr, out, nullptr, E_);
    } else {
        // fallback: round-4 path (in-kernel split, fp32 weights)
        us*    H1_0 = (us*)ws;
        us*    H1_1 = (us*)(ws + ((size_t)128 << 20));
        float* SCo  = (float*)ws;
        us*    MB   = (us*)(ws + ((size_t)128 << 20));
        us* H2_0 = (us*)d_out;
        us* H2_1 = (us*)d_out + (size_t)B_ * Q_;
        float* H1Fo = (float*)ws;
        float* H2Fo = (float*)(ws + ((size_t)128 << 20));
        float* SCFo = (float*)(ws + ((size_t)192 << 20));
        gemm3p<3, true,  true,  true ><<<dim3(2 * Q_ / 128, B_ / 128), blk, 0, stream>>>(
            x, nullptr, W1, H1_0, H1_1, B_, 2 * Q_, Q_);
        gemm3p<3, false, true,  true ><<<dim3(Q_ / 128, B_ / 128), blk, 0, stream>>>(
            H1_0, H1_1, W2, H2_0, H2_1, B_, Q_, 2 * Q_);
        gemm3p<3, false, false, false><<<dim3(Q_ / 128, B_ / 128), blk, 0, stream>>>(
            H2_0, H2_1, W3, SCo, nullptr, B_, Q_, Q_);
        row_argmax_flag<<<dim3(B_ / 4), blk, 0, stream>>>(SCo, KV, FLAGS, CNT, 1e-3f);
        rescore_gemm<Q_,     true,  true ><<<dim3(4096), blk, 0, stream>>>(x,    W1, H1Fo, FLAGS, CNT, 2 * Q_, CAPF);
        rescore_gemm<2 * Q_, false, true ><<<dim3(2048), blk, 0, stream>>>(H1Fo, W2, H2Fo, FLAGS, CNT, Q_,     CAPF);
        rescore_gemm<Q_,     false, false><<<dim3(2048), blk, 0, stream>>>(H2Fo, W3, SCFo, FLAGS, CNT, Q_,     CAPF);
        rescore_argmax<<<dim3(64), blk, 0, stream>>>(SCFo, FLAGS, CNT, KV, CAPF);
        topk_mask_radix<<<dim3(B_ / 4), blk, 0, stream>>>(x, KV, MB);
        gemm3p<1, false, false, false><<<dim3(E_ / 128, B_ / 128), blk, 0, stream>>>(
            MB, nullptr, Wc, out, nullptr, B_, E_, Q_);
    }
}

// Round 15
// 1050.958 us; speedup vs baseline: 1.2353x; 1.0124x over previous
//
#include <hip/hip_runtime.h>
#include <stdint.h>

#define B_  32768
#define Q_  1024
#define E_  1024
#define CAPF  4096    // stage-1 flag capacity (expected ~1900 at theta=0.008)
#define CAPF2 1024    // stage-2 flag capacity (rows refined by fp64)

typedef __attribute__((ext_vector_type(8))) short bf16x8;
typedef __attribute__((ext_vector_type(8))) _Float16 f16x8;
typedef __attribute__((ext_vector_type(8))) unsigned short u16x8;
typedef __attribute__((ext_vector_type(4))) float f32x4;
typedef unsigned short us;

__device__ __forceinline__ f32x4 MFMA16(bf16x8 a, bf16x8 b, f32x4 c) {
    return __builtin_amdgcn_mfma_f32_16x16x32_bf16(a, b, c, 0, 0, 0);
}
__device__ __forceinline__ f32x4 MFMA16H(bf16x8 a, bf16x8 b, f32x4 c) {
    return __builtin_amdgcn_mfma_f32_16x16x32_f16(
        __builtin_bit_cast(f16x8, a), __builtin_bit_cast(f16x8, b), c, 0, 0, 0);
}

__device__ __forceinline__ us f2bf(float v) {   // RNE fp32->bf16
    unsigned u = __float_as_uint(v);
    u += 0x7FFFu + ((u >> 16) & 1u);
    return (us)(u >> 16);
}
__device__ __forceinline__ float bf2f(us b) {
    return __uint_as_float(((unsigned)b) << 16);
}
__device__ __forceinline__ us f2h(float v) {    // RNE fp32->fp16 bits
    _Float16 h = (_Float16)v;
    return __builtin_bit_cast(unsigned short, h);
}

// ---------------- plane prep kernels (memory-bound, run once) ---------------
__global__ __launch_bounds__(256)
void cvt4_h(const float* __restrict__ s0, us* __restrict__ d0, int e0,
            const float* __restrict__ s1, us* __restrict__ d1, int e1,
            const float* __restrict__ s2, us* __restrict__ d2, int e2,
            const float* __restrict__ s3, us* __restrict__ d3, int e3) {
    int i = blockIdx.x * 256 + threadIdx.x;
    const int stride = gridDim.x * 256;
    for (; i < e3; i += stride) {
        const float* s; us* d; int j;
        if (i < e0)      { s = s0; d = d0; j = i; }
        else if (i < e1) { s = s1; d = d1; j = i - e0; }
        else if (i < e2) { s = s2; d = d2; j = i - e1; }
        else             { s = s3; d = d3; j = i - e2; }
        float4 a = ((const float4*)s)[j * 2];
        float4 b = ((const float4*)s)[j * 2 + 1];
        float f[8] = {a.x, a.y, a.z, a.w, b.x, b.y, b.z, b.w};
        u16x8 h;
#pragma unroll
        for (int k = 0; k < 8; ++k) h[k] = f2h(f[k]);
        ((u16x8*)d)[j] = h;
    }
}

__global__ __launch_bounds__(256)
void split3_k(const float* __restrict__ s0, us* __restrict__ h0, us* __restrict__ l0, int e0,
              const float* __restrict__ s1, us* __restrict__ h1, us* __restrict__ l1, int e1,
              const float* __restrict__ s2, us* __restrict__ h2, us* __restrict__ l2, int e2) {
    int i = blockIdx.x * 256 + threadIdx.x;
    const int stride = gridDim.x * 256;
    for (; i < e2; i += stride) {
        const float* s; us *dh, *dl; int j;
        if (i < e0)      { s = s0; dh = h0; dl = l0; j = i; }
        else if (i < e1) { s = s1; dh = h1; dl = l1; j = i - e0; }
        else             { s = s2; dh = h2; dl = l2; j = i - e1; }
        float4 a = ((const float4*)s)[j * 2];
        float4 b = ((const float4*)s)[j * 2 + 1];
        float f[8] = {a.x, a.y, a.z, a.w, b.x, b.y, b.z, b.w};
        u16x8 h, l;
#pragma unroll
        for (int k = 0; k < 8; ++k) {
            us c0 = f2bf(f[k]);
            h[k] = c0;
            l[k] = f2bf(f[k] - bf2f(c0));   // exact residual (Sterbenz)
        }
        ((u16x8*)dh)[j] = h;
        ((u16x8*)dl)[j] = l;
    }
}

__global__ __launch_bounds__(256)
void cvt_plane_k(const float* __restrict__ in, us* __restrict__ hi, int n8) {
    int i = blockIdx.x * 256 + threadIdx.x;
    const int stride = gridDim.x * 256;
    for (; i < n8; i += stride) {
        float4 a = ((const float4*)in)[i * 2];
        float4 b = ((const float4*)in)[i * 2 + 1];
        float f[8] = {a.x, a.y, a.z, a.w, b.x, b.y, b.z, b.w};
        u16x8 h;
#pragma unroll
        for (int j = 0; j < 8; ++j) h[j] = f2bf(f[j]);
        ((u16x8*)hi)[i] = h;
    }
}

// gather flagged rows of fp32 x and split into bf16 hi/lo planes [CAPF][Q]
__global__ __launch_bounds__(256)
void gather_split(const float* __restrict__ X, const int* __restrict__ flags,
                  const int* __restrict__ cnt, us* __restrict__ G0,
                  us* __restrict__ G1) {
    const int n = min(*cnt, CAPF);
    for (int it = blockIdx.x; it < n; it += gridDim.x) {
        int row = flags[it];
        if ((unsigned)row >= B_) row = 0;            // replay-safety clamp
        float4 v = ((const float4*)(X + (size_t)row * Q_))[threadIdx.x];
        float f[4] = {v.x, v.y, v.z, v.w};
        us h[4], l[4];
#pragma unroll
        for (int j = 0; j < 4; ++j) {
            h[j] = f2bf(f[j]);
            l[j] = f2bf(f[j] - bf2f(h[j]));
        }
        *(uint2*)&G0[(size_t)it * Q_ + threadIdx.x * 4] = *(uint2*)h;
        *(uint2*)&G1[(size_t)it * Q_ + threadIdx.x * 4] = *(uint2*)l;
    }
}

// sum SPLITS fp32 partials; MODE 0: fp32 out; MODE 1: relu + bf16 hi/lo planes
template<int SPLITS, int MODE>
__global__ __launch_bounds__(256)
void finalize_k(const float* __restrict__ P, size_t pstride,
                us* __restrict__ o0, us* __restrict__ o1,
                float* __restrict__ of, const int* __restrict__ cnt, int N) {
    const int n = min(*cnt, CAPF);
    const int total4 = n * (N >> 2);
    int i = blockIdx.x * 256 + threadIdx.x;
    const int stride = gridDim.x * 256;
    for (; i < total4; i += stride) {
        float4 s = ((const float4*)P)[i];
#pragma unroll
        for (int sp = 1; sp < SPLITS; ++sp) {
            float4 p = *(const float4*)(P + (size_t)sp * pstride + (size_t)i * 4);
            s.x += p.x; s.y += p.y; s.z += p.z; s.w += p.w;
        }
        if constexpr (MODE == 0) {
            ((float4*)of)[i] = s;
        } else {
            float f[4] = {fmaxf(s.x, 0.f), fmaxf(s.y, 0.f),
                          fmaxf(s.z, 0.f), fmaxf(s.w, 0.f)};
            us h[4], l[4];
#pragma unroll
            for (int j = 0; j < 4; ++j) {
                h[j] = f2bf(f[j]);
                l[j] = f2bf(f[j] - bf2f(h[j]));
            }
            *(uint2*)&o0[(size_t)i * 4] = *(uint2*)h;
            *(uint2*)&o1[(size_t)i * 4] = *(uint2*)l;
        }
    }
}

// merge per-tile top-2 candidates -> KV + near-tie flags (theta)
__global__ __launch_bounds__(256)
void argmax_merge(const float4* __restrict__ PT, int gx, int* __restrict__ KV,
                  int* __restrict__ flags, int* __restrict__ cnt, float theta) {
    const int row = blockIdx.x * 256 + threadIdx.x;
    float b1 = -3.4e38f, b2 = -3.4e38f; int i1 = 0;
    for (int ti = 0; ti < gx; ++ti) {
        float4 e = PT[(size_t)row * gx + ti];
        float o1 = e.x, o2 = e.y; int oi = __float_as_int(e.z);
        if (o1 > b1 || (o1 == b1 && oi < i1)) {
            b2 = fmaxf(b1, o2);
            b1 = o1; i1 = oi;
        } else {
            b2 = fmaxf(b2, o1);        // o2 <= o1, covered
        }
    }
    KV[row] = i1 + 1;
    if (b1 - b2 < theta) {
        int p = atomicAdd(cnt, 1);
        if (p < CAPF) flags[p] = row;
    }
}

// ============================================================================
// 256x256-tile GEMM (round-8 verified core). 8 waves (2Mx4N), BK=32, 4-slot
// whole-tile LDS ring (128 KiB), safe deep pipeline.
// NSEG=3: acc = A0B0 + A0B1 + A1B0 over K'=3K (fp32-grade split-bf16).
// EMIT: 0=fp32, 1=bf16 hi/lo pair, 2=fp16, 3=fused per-tile top-2 argmax
// (writes float4{b1,b2,idx,0} to Cp0[row*gx + ntile]). FP16: f16 MFMA.
// ============================================================================
#define LGKM0() asm volatile("s_waitcnt lgkmcnt(0)" ::: "memory")
#define VMC8()  asm volatile("s_waitcnt vmcnt(8)" ::: "memory")
#define VMC0A() asm volatile("s_waitcnt vmcnt(0)" ::: "memory")
#define BAR()   __builtin_amdgcn_s_barrier()
#define RD_AB(Aarr, Barr, slot) { \
    const us* _la = &LA[(slot) * 8192]; const us* _lb = &LB[(slot) * 8192]; \
    _Pragma("unroll") for (int mf = 0; mf < 8; ++mf) Aarr[mf] = *(const bf16x8*)&_la[ago[mf]]; \
    _Pragma("unroll") for (int nf = 0; nf < 4; ++nf) Barr[nf] = *(const bf16x8*)&_lb[bgo[nf]]; }
#define CLX(AF, BF) { __builtin_amdgcn_s_setprio(1); \
    _Pragma("unroll") for (int mf = 0; mf < 8; ++mf) { \
        _Pragma("unroll") for (int nf = 0; nf < 4; ++nf) { \
            if constexpr (FP16) acc[mf][nf] = MFMA16H(AF[mf], BF[nf], acc[mf][nf]); \
            else               acc[mf][nf] = MFMA16 (AF[mf], BF[nf], acc[mf][nf]); } } \
    __builtin_amdgcn_s_setprio(0); }

template<int NSEG, int K, int EMIT, bool RELU, bool FP16>
__global__ __launch_bounds__(512, 2)
void gemm4r(const us* __restrict__ A0p, const us* __restrict__ A1p,
            const us* __restrict__ B0p, const us* __restrict__ B1p,
            void* __restrict__ Cp0, void* __restrict__ Cp1, int N) {
    constexpr int TPS = K / 32;
    constexpr int NT  = NSEG * TPS;
    static_assert(NT % 2 == 0 && NT >= 4, "shape");
    __shared__ __align__(16) us LA[4 * 8192];
    __shared__ __align__(16) us LB[4 * 8192];

    const int t = threadIdx.x;
    const int wv = t >> 6, lane = t & 63;
    const int lanelo = lane & 15, kq = lane >> 4;
    const int wm = wv >> 2, wn = wv & 3;

    const int q8 = gridDim.x >> 3;       // grid % 8 == 0 (T1 bijective swizzle)
    const int logical = ((int)blockIdx.x & 7) * q8 + ((int)blockIdx.x >> 3);
    const int gx = N >> 8;
    const int m0 = (logical / gx) * 256, n0 = (logical % gx) * 256;

    int soff[2], ldst[2];
#pragma unroll
    for (int i = 0; i < 2; ++i) {
        int s = i * 512 + t;
        int row = s >> 2, c = s & 3;
        soff[i] = row * K + (c ^ ((row >> 1) & 3)) * 8;
        ldst[i] = (i * 512 + wv * 64) * 8;
    }
    int ago[8], bgo[4];
#pragma unroll
    for (int mf = 0; mf < 8; ++mf) {
        int row = wm * 128 + mf * 16 + lanelo;
        ago[mf] = (row * 4 + (kq ^ ((row >> 1) & 3))) * 8;
    }
#pragma unroll
    for (int nf = 0; nf < 4; ++nf) {
        int row = wn * 64 + nf * 16 + lanelo;
        bgo[nf] = (row * 4 + (kq ^ ((row >> 1) & 3))) * 8;
    }

    auto stage = [&](int tv) {
        int slot = tv & 3;
        int seg = tv / TPS;
        int kb  = (tv - seg * TPS) * 32;
        const us* Ap = (NSEG == 1 || seg < 2) ? A0p : A1p;
        const us* Bp = (NSEG == 3 && seg == 1) ? B1p : B0p;
        const us* Abase = Ap + (size_t)m0 * K + kb;
        const us* Bbase = Bp + (size_t)n0 * K + kb;
        us* dA = &LA[slot * 8192];
        us* dB = &LB[slot * 8192];
#pragma unroll
        for (int i = 0; i < 2; ++i) {
            __builtin_amdgcn_global_load_lds(
                (const __attribute__((address_space(1))) void*)(Abase + soff[i]),
                (__attribute__((address_space(3))) void*)(dA + ldst[i]), 16, 0, 0);
            __builtin_amdgcn_global_load_lds(
                (const __attribute__((address_space(1))) void*)(Bbase + soff[i]),
                (__attribute__((address_space(3))) void*)(dB + ldst[i]), 16, 0, 0);
        }
    };

    f32x4 acc[8][4];
#pragma unroll
    for (int i = 0; i < 8; ++i)
#pragma unroll
        for (int j = 0; j < 4; ++j) acc[i][j] = (f32x4){0.f, 0.f, 0.f, 0.f};

    bf16x8 aE[8], bE[4], aO[8], bO[4];

    stage(0); stage(1); stage(2);
    VMC8();  BAR();
    RD_AB(aE, bE, 0);
    stage(3);
    LGKM0(); VMC8(); BAR();

    for (int tt = 0; tt < NT; tt += 2) {
        RD_AB(aO, bO, (tt + 1) & 3);
        { int tv = tt + 4; if (tv > NT - 1) tv = NT - 1; stage(tv); }
        CLX(aE, bE);
        LGKM0(); VMC8(); BAR();
        { int tn = (tt + 2 < NT) ? (tt + 2) : (NT - 1);
          RD_AB(aE, bE, tn & 3); }
        { int tv = tt + 5; if (tv > NT - 1) tv = NT - 1; stage(tv); }
        CLX(aO, bO);
        LGKM0(); VMC8(); BAR();
    }

    if constexpr (EMIT == 3) {
        // fused per-tile top-2 argmax. Drain tail stages before reusing LDS
        // (r7 lesson: each wave's own vmcnt(0), then barrier -> all writes done)
        VMC0A(); BAR();
        float* SD = (float*)LA;   // [256 rows][4 wn][4 floats]
#pragma unroll
        for (int mf = 0; mf < 8; ++mf)
#pragma unroll
            for (int r = 0; r < 4; ++r) {
                float b1 = -3.4e38f, b2 = -3.4e38f; int i1 = 0;
#pragma unroll
                for (int nf = 0; nf < 4; ++nf) {
                    float v = acc[mf][nf][r];
                    int c = wn * 64 + nf * 16 + lanelo;
                    if (v > b1 || (v == b1 && c < i1)) { b2 = b1; b1 = v; i1 = c; }
                    else if (v > b2) b2 = v;
                }
#pragma unroll
                for (int m = 1; m < 16; m <<= 1) {   // reduce 16 lanelo lanes
                    float o1 = __shfl_xor(b1, m);
                    int   oi = __shfl_xor(i1, m);
                    float o2 = __shfl_xor(b2, m);
                    if (o1 > b1 || (o1 == b1 && oi < i1)) {
                        b2 = fmaxf(b1, o2);
                        b1 = o1; i1 = oi;
                    } else {
                        b2 = fmaxf(b2, o1);
                    }
                }
                if (lanelo == 0) {
                    int rl = wm * 128 + mf * 16 + kq * 4 + r;
                    SD[(rl * 4 + wn) * 4 + 0] = b1;
                    SD[(rl * 4 + wn) * 4 + 1] = b2;
                    SD[(rl * 4 + wn) * 4 + 2] = __int_as_float(i1);
                }
            }
        BAR();
        if (t < 256) {                                // one thread per row
            float b1 = -3.4e38f, b2 = -3.4e38f; int i1 = 0;
#pragma unroll
            for (int w2 = 0; w2 < 4; ++w2) {          // ascending wn = asc col
                float o1 = SD[(t * 4 + w2) * 4 + 0];
                float o2 = SD[(t * 4 + w2) * 4 + 1];
                int   oi = __float_as_int(SD[(t * 4 + w2) * 4 + 2]);
                if (o1 > b1 || (o1 == b1 && oi < i1)) {
                    b2 = fmaxf(b1, o2);
                    b1 = o1; i1 = oi;
                } else {
                    b2 = fmaxf(b2, o1);
                }
            }
            float4 e; e.x = b1; e.y = b2; e.z = __int_as_float(n0 + i1); e.w = 0.f;
            ((float4*)Cp0)[(size_t)(m0 + t) * gx + (n0 >> 8)] = e;
        }
        return;
    }

    // epilogue: C/D layout col=lane&15, row=(lane>>4)*4+reg (m89/m91)
#pragma unroll
    for (int mf = 0; mf < 8; ++mf)
#pragma unroll
        for (int nf = 0; nf < 4; ++nf)
#pragma unroll
            for (int r = 0; r < 4; ++r) {
                int row = m0 + wm * 128 + mf * 16 + kq * 4 + r;
                int col = n0 + wn * 64 + nf * 16 + lanelo;
                float v = acc[mf][nf][r];
                if constexpr (RELU) v = fmaxf(v, 0.f);
                if constexpr (EMIT == 1) {
                    us c0 = f2bf(v);
                    ((us*)Cp0)[(size_t)row * N + col] = c0;
                    ((us*)Cp1)[(size_t)row * N + col] = f2bf(v - bf2f(c0));
                } else if constexpr (EMIT == 2) {
                    ((us*)Cp0)[(size_t)row * N + col] = f2h(v);
                } else {
                    ((float*)Cp0)[(size_t)row * N + col] = v;
                }
            }
}

// ============================================================================
// 128x128-tile split-K all-plane GEMM for the gathered pass. grid.y = split.
// ============================================================================
template<int NPASS, int SPLITS>
__global__ __launch_bounds__(256, 4)
void gemm_sp(const us* __restrict__ A0, const us* __restrict__ A1,
             const us* __restrict__ B0, const us* __restrict__ B1,
             float* __restrict__ P, size_t pstride,
             int N, int K, const int* __restrict__ ncnt) {
    __shared__ __align__(16) us A0s[128 * 32];
    __shared__ __align__(16) us B0s[128 * 32];

    const int t = threadIdx.x;
    const int wave = t >> 6, lane = t & 63;
    const int lanelo = lane & 15, kq = lane >> 4;
    const int wm = wave >> 1, wn = wave & 1;
    const int q8 = gridDim.x >> 3;
    const int logical = ((int)blockIdx.x & 7) * q8 + ((int)blockIdx.x >> 3);
    const int gx = N >> 7;
    const int m0 = (logical / gx) * 128, n0 = (logical % gx) * 128;
    const int split = blockIdx.y;

    int nn = *ncnt; if (nn > CAPF) nn = CAPF;
    if (m0 >= ((nn + 127) & ~127)) return;

    const int Ks = K / SPLITS;
    const int kbase = split * Ks;
    const int tps = Ks >> 5;

    f32x4 acc[4][4];
#pragma unroll
    for (int i = 0; i < 4; ++i)
#pragma unroll
        for (int j = 0; j < 4; ++j) acc[i][j] = (f32x4){0.f, 0.f, 0.f, 0.f};

    for (int vt = 0; vt < NPASS * tps; ++vt) {
        const int seg = vt / tps;
        const int kt  = kbase + (vt - seg * tps) * 32;
        const us* Ap = (NPASS == 1 || seg < 2) ? A0 : A1;
        const us* Bp = (NPASS == 3 && seg == 1) ? B1 : B0;
        __syncthreads();
#pragma unroll
        for (int g = 0; g < 2; ++g) {
            int c = (g * 4 + wave) * 64 + lane;
            int row = c >> 2;
            int koff = (c & 3) ^ ((row >> 1) & 3);   // pre-swizzled source
            size_t offa = (size_t)(m0 + row) * K + kt + koff * 8;
            size_t offb = (size_t)(n0 + row) * K + kt + koff * 8;
            int dst = (g * 4 + wave) * 512;
            __builtin_amdgcn_global_load_lds(
                (const __attribute__((address_space(1))) void*)(Ap + offa),
                (__attribute__((address_space(3))) void*)&A0s[dst], 16, 0, 0);
            __builtin_amdgcn_global_load_lds(
                (const __attribute__((address_space(1))) void*)(Bp + offb),
                (__attribute__((address_space(3))) void*)&B0s[dst], 16, 0, 0);
        }
        __syncthreads();

        bf16x8 a0[4];
#pragma unroll
        for (int mf = 0; mf < 4; ++mf) {
            int ar = wm * 64 + mf * 16 + lanelo;
            int ac = ar * 4 + (kq ^ ((ar >> 1) & 3));
            a0[mf] = *(const bf16x8*)&A0s[ac * 8];
        }
#pragma unroll
        for (int nf = 0; nf < 4; ++nf) {
            int br = wn * 64 + nf * 16 + lanelo;
            int bc = br * 4 + (kq ^ ((br >> 1) & 3));
            bf16x8 vb0 = *(const bf16x8*)&B0s[bc * 8];
#pragma unroll
            for (int mf = 0; mf < 4; ++mf) acc[mf][nf] = MFMA16(a0[mf], vb0, acc[mf][nf]);
        }
    }

    float* Pd = P + (size_t)split * pstride;
#pragma unroll
    for (int mf = 0; mf < 4; ++mf)
#pragma unroll
        for (int nf = 0; nf < 4; ++nf)
#pragma unroll
            for (int r = 0; r < 4; ++r) {
                int row = m0 + wm * 64 + mf * 16 + kq * 4 + r;
                int col = n0 + wn * 64 + nf * 16 + lanelo;
                Pd[(size_t)row * N + col] = acc[mf][nf][r];
            }
}

// ---------------- fallback GEMM (round-4 path, in-kernel split) -------------
__device__ __forceinline__ int chunk_of(int row, int koff) {
    return row * 4 + (koff ^ (row & 3));
}

template<int NPASS>
__device__ __forceinline__ void split_store(us* S0, us* S1,
                                            int rowX, int koffX, float4 a, float4 b) {
    int ch = chunk_of(rowX, koffX);
    float f[8] = {a.x, a.y, a.z, a.w, b.x, b.y, b.z, b.w};
    bf16x8 lo, hi;
#pragma unroll
    for (int j = 0; j < 8; ++j) {
        us c0 = f2bf(f[j]);
        lo[j] = (short)c0;
        hi[j] = (short)f2bf(f[j] - bf2f(c0));
    }
    *(bf16x8*)&S0[ch * 8] = lo;
    if constexpr (NPASS == 3) *(bf16x8*)&S1[ch * 8] = hi;
}

template<int NPASS, bool AF32, bool RELU, bool EMITP>
__global__ __launch_bounds__(256, 2)
void gemm3p(const void* __restrict__ Ap0, const void* __restrict__ Ap1,
            const float* __restrict__ Wf,
            void* __restrict__ Cp0, void* __restrict__ Cp1,
            int M, int N, int K) {
    __shared__ __align__(16) us A0s[128 * 32];
    __shared__ __align__(16) us B0s[128 * 32];
    __shared__ __align__(16) us A1s[(NPASS == 3) ? 128 * 32 : 8];
    __shared__ __align__(16) us B1s[(NPASS == 3) ? 128 * 32 : 8];

    const int t = threadIdx.x;
    const int wave = t >> 6, lane = t & 63;
    const int lanelo = lane & 15, kq = lane >> 4;
    const int wm = wave >> 1, wn = wave & 1;
    const int m0 = blockIdx.y * 128, n0 = blockIdx.x * 128;
    const int brow = t >> 1, bhalf = t & 1;

    f32x4 acc[4][4];
#pragma unroll
    for (int i = 0; i < 4; ++i)
#pragma unroll
        for (int j = 0; j < 4; ++j) acc[i][j] = (f32x4){0.f, 0.f, 0.f, 0.f};

    for (int kt = 0; kt < K; kt += 32) {
        __syncthreads();
        const float* wp = Wf + (size_t)(n0 + brow) * K + kt + bhalf * 16;
        float4 v0 = *(const float4*)(wp + 0);
        float4 v1 = *(const float4*)(wp + 4);
        float4 v2 = *(const float4*)(wp + 8);
        float4 v3 = *(const float4*)(wp + 12);
        if constexpr (AF32) {
            const float* ap = (const float*)Ap0 + (size_t)(m0 + brow) * K + kt + bhalf * 16;
            float4 u0 = *(const float4*)(ap + 0);
            float4 u1 = *(const float4*)(ap + 4);
            float4 u2 = *(const float4*)(ap + 8);
            float4 u3 = *(const float4*)(ap + 12);
            split_store<NPASS>(A0s, A1s, brow, bhalf * 2 + 0, u0, u1);
            split_store<NPASS>(A0s, A1s, brow, bhalf * 2 + 1, u2, u3);
        } else {
#pragma unroll
            for (int g = 0; g < 2; ++g) {
                int c = (g * 4 + wave) * 64 + lane;
                int row = c >> 2;
                int koff = (c & 3) ^ (row & 3);
                const us* s0 = (const us*)Ap0 + (size_t)(m0 + row) * K + kt + koff * 8;
                __builtin_amdgcn_global_load_lds(
                    (const __attribute__((address_space(1))) void*)s0,
                    (__attribute__((address_space(3))) void*)&A0s[(size_t)(g * 4 + wave) * 512],
                    16, 0, 0);
                if constexpr (NPASS == 3) {
                    const us* s1 = (const us*)Ap1 + (size_t)(m0 + row) * K + kt + koff * 8;
                    __builtin_amdgcn_global_load_lds(
                        (const __attribute__((address_space(1))) void*)s1,
                        (__attribute__((address_space(3))) void*)&A1s[(size_t)(g * 4 + wave) * 512],
                        16, 0, 0);
                }
            }
        }
        split_store<NPASS>(B0s, B1s, brow, bhalf * 2 + 0, v0, v1);
        split_store<NPASS>(B0s, B1s, brow, bhalf * 2 + 1, v2, v3);
        __syncthreads();

        bf16x8 a0[4], a1[4];
#pragma unroll
        for (int mf = 0; mf < 4; ++mf) {
            int ar = wm * 64 + mf * 16 + lanelo;
            int ac = chunk_of(ar, kq);
            a0[mf] = *(const bf16x8*)&A0s[ac * 8];
            if constexpr (NPASS == 3) a1[mf] = *(const bf16x8*)&A1s[ac * 8];
        }
#pragma unroll
        for (int nf = 0; nf < 4; ++nf) {
            int br = wn * 64 + nf * 16 + lanelo;
            int bc = chunk_of(br, kq);
            bf16x8 vb0 = *(const bf16x8*)&B0s[bc * 8];
#pragma unroll
            for (int mf = 0; mf < 4; ++mf) acc[mf][nf] = MFMA16(a0[mf], vb0, acc[mf][nf]);
            if constexpr (NPASS == 3) {
                bf16x8 vb1 = *(const bf16x8*)&B1s[bc * 8];
#pragma unroll
                for (int mf = 0; mf < 4; ++mf) acc[mf][nf] = MFMA16(a0[mf], vb1, acc[mf][nf]);
#pragma unroll
                for (int mf = 0; mf < 4; ++mf) acc[mf][nf] = MFMA16(a1[mf], vb0, acc[mf][nf]);
            }
        }
    }

#pragma unroll
    for (int mf = 0; mf < 4; ++mf)
#pragma unroll
        for (int nf = 0; nf < 4; ++nf)
#pragma unroll
            for (int r = 0; r < 4; ++r) {
                int row = m0 + wm * 64 + mf * 16 + kq * 4 + r;
                int col = n0 + wn * 64 + nf * 16 + lanelo;
                float v = acc[mf][nf][r];
                if constexpr (RELU) v = fmaxf(v, 0.f);
                if constexpr (EMITP) {
                    us c0 = f2bf(v);
                    ((us*)Cp0)[(size_t)row * N + col] = c0;
                    ((us*)Cp1)[(size_t)row * N + col] = f2bf(v - bf2f(c0));
                } else {
                    ((float*)Cp0)[(size_t)row * N + col] = v;
                }
            }
}

// k[row] = argmax+1 (first occurrence); flag rows whose top-2 gap < theta
__global__ __launch_bounds__(256)
void row_argmax_flag(const float* __restrict__ S, int* __restrict__ KV,
                     int* __restrict__ flags, int* __restrict__ cnt, float theta) {
    int row = blockIdx.x * 4 + (threadIdx.x >> 6);
    int lane = threadIdx.x & 63;
    const float* s = S + (size_t)row * Q_;
    float b1 = -3.4e38f, b2 = -3.4e38f; int i1 = 0;
    for (int j = lane; j < Q_; j += 64) {
        float v = s[j];
        if (v > b1) { b2 = b1; b1 = v; i1 = j; }
        else if (v > b2) b2 = v;
    }
#pragma unroll
    for (int m = 1; m < 64; m <<= 1) {
        float o1 = __shfl_xor(b1, m);
        int   oi = __shfl_xor(i1, m);
        float o2 = __shfl_xor(b2, m);
        if (o1 > b1 || (o1 == b1 && oi < i1)) {
            b2 = fmaxf(b1, o2);
            b1 = o1; i1 = oi;
        } else {
            b2 = fmaxf(b2, o1);
        }
    }
    if (lane == 0) {
        KV[row] = i1 + 1;
        if (b1 - b2 < theta) {
            int p = atomicAdd(cnt, 1);
            if (p < CAPF) flags[p] = row;
        }
    }
}

// argmax over gathered (pass-2) scores: scatter k, flag near-ties for fp64
__global__ __launch_bounds__(256)
void g_argmax_flag2(const float* __restrict__ SCg, const int* __restrict__ flags,
                    const int* __restrict__ cnt, int* __restrict__ KV,
                    int* __restrict__ flags2, int* __restrict__ cnt2) {
    const int lane = threadIdx.x & 63, wv = threadIdx.x >> 6;
    const int n = min(*cnt, CAPF);
    for (int it = blockIdx.x * 4 + wv; it < n; it += gridDim.x * 4) {
        const float* s = SCg + (size_t)it * Q_;
        float b1 = -3.4e38f, b2 = -3.4e38f; int i1 = 0;
        for (int j = lane; j < Q_; j += 64) {
            float v = s[j];
            if (v > b1) { b2 = b1; b1 = v; i1 = j; }
            else if (v > b2) b2 = v;
        }
#pragma unroll
        for (int m = 1; m < 64; m <<= 1) {
            float o1 = __shfl_xor(b1, m);
            int   oi = __shfl_xor(i1, m);
            float o2 = __shfl_xor(b2, m);
            if (o1 > b1 || (o1 == b1 && oi < i1)) {
                b2 = fmaxf(b1, o2);
                b1 = o1; i1 = oi;
            } else {
                b2 = fmaxf(b2, o1);
            }
        }
        if (lane == 0) {
            int r = flags[it];
            if ((unsigned)r < B_) {
                KV[r] = i1 + 1;
                if (b1 - b2 < 1e-3f) {
                    int p = atomicAdd(cnt2, 1);
                    if (p < CAPF2) flags2[p] = r;
                }
            }
        }
    }
}

// ---- parallel coalesced rescore (fp64): K compile-time, float4 loads ----
template<int K, bool IN_BY_FLAG, bool RELU>
__global__ __launch_bounds__(256)
void rescore_gemm(const float* __restrict__ IN, const float* __restrict__ W,
                  float* __restrict__ OUT, const int* __restrict__ flags,
                  const int* __restrict__ cnt, int N, int cap) {
    __shared__ float xr[K];
    const int t = threadIdx.x, lane = t & 63, wv = t >> 6;
    const int n = min(*cnt, cap);
    const int chunks = N >> 4;
    for (int w = blockIdx.x; w < n * chunks; w += gridDim.x) {
        const int it = w / chunks, ch = w - it * chunks;
        int srow = IN_BY_FLAG ? flags[it] : it;
        if (IN_BY_FLAG && (unsigned)srow >= B_) srow = 0;   // replay-safety clamp
        const float* rp = IN + (size_t)srow * K;
        __syncthreads();
#pragma unroll
        for (int p = t; p < K / 4; p += 256)
            ((float4*)xr)[p] = ((const float4*)rp)[p];
        __syncthreads();
#pragma unroll
        for (int jj = 0; jj < 4; ++jj) {
            const int col = ch * 16 + wv * 4 + jj;
            const float* wr = W + (size_t)col * K;
            double a0 = 0.0, a1 = 0.0;
#pragma unroll
            for (int i = 0; i < K / 256; ++i) {
                const int k = i * 256 + lane * 4;
                float4 w4 = *(const float4*)(wr + k);
                float4 x4 = *(const float4*)(xr + k);
                a0 += (double)x4.x * w4.x + (double)x4.y * w4.y;
                a1 += (double)x4.z * w4.z + (double)x4.w * w4.w;
            }
            double a = a0 + a1;
#pragma unroll
            for (int m = 1; m < 64; m <<= 1) a += __shfl_xor(a, m);
            if (lane == 0) {
                float v = (float)a;
                if (RELU) v = fmaxf(v, 0.f);
                OUT[(size_t)it * N + col] = v;
            }
        }
    }
}

// final exact argmax over fp64-rescored rows, first-occurrence tie-break
__global__ __launch_bounds__(256)
void rescore_argmax(const float* __restrict__ SCF, const int* __restrict__ flags,
                    const int* __restrict__ cnt, int* __restrict__ KV, int cap) {
    const int lane = threadIdx.x & 63, wv = threadIdx.x >> 6;
    const int n = min(*cnt, cap);
    for (int it = blockIdx.x * 4 + wv; it < n; it += gridDim.x * 4) {
        const float* s = SCF + (size_t)it * Q_;
        float best = -3.4e38f; int bi = 0;
        for (int j = lane; j < Q_; j += 64) {
            float v = s[j];
            if (v > best) { best = v; bi = j; }
        }
#pragma unroll
        for (int m = 1; m < 64; m <<= 1) {
            float ov = __shfl_xor(best, m); int oi = __shfl_xor(bi, m);
            if (ov > best || (ov == best && oi < bi)) { best = ov; bi = oi; }
        }
        if (lane == 0) {
            int r = flags[it];
            if ((unsigned)r < B_) KV[r] = bi + 1;
        }
    }
}

// ---- stable top-k mask via in-register bit-descent radix select ----
__global__ __launch_bounds__(256)
void topk_mask_radix(const float* __restrict__ X, const int* __restrict__ KV,
                     us* __restrict__ Mout) {
    const int row  = blockIdx.x * 4 + (threadIdx.x >> 6);
    const int lane = threadIdx.x & 63;
    const float* x = X + (size_t)row * Q_;

    unsigned u[16];
#pragma unroll
    for (int j4 = 0; j4 < 4; ++j4) {
        float4 v = *(const float4*)(x + lane * 16 + j4 * 4);
        float f[4] = {v.x, v.y, v.z, v.w};
#pragma unroll
        for (int e = 0; e < 4; ++e) {
            unsigned fb = __float_as_uint(f[e]);
            u[j4 * 4 + e] = (fb & 0x80000000u) ? ~fb : (fb | 0x80000000u);
        }
    }
    const int k = KV[row];

    unsigned p = 0;
#pragma unroll
    for (int b = 31; b >= 0; --b) {
        unsigned q = p | (1u << b);
        int c = 0;
#pragma unroll
        for (int j = 0; j < 16; ++j) c += (u[j] >= q);
#pragma unroll
        for (int m = 1; m < 64; m <<= 1) c += __shfl_xor(c, m);
        if (c >= k) p = q;
    }

    int gt = 0, eqloc = 0;
#pragma unroll
    for (int j = 0; j < 16; ++j) { gt += (u[j] > p); eqloc += (u[j] == p); }
    int gtot = gt;
#pragma unroll
    for (int m = 1; m < 64; m <<= 1) gtot += __shfl_xor(gtot, m);
    int scan = eqloc;
#pragma unroll
    for (int d = 1; d < 64; d <<= 1) {
        int o = __shfl_up(scan, d);
        if (lane >= d) scan += o;
    }
    int run = scan - eqloc;
    const int quota = k - gtot;

    us m16[16];
#pragma unroll
    for (int j = 0; j < 16; ++j) {
        bool one;
        if (u[j] > p) one = true;
        else if (u[j] == p) { one = (run < quota); ++run; }
        else one = false;
        m16[j] = one ? (us)0x3F80 : (us)0;
    }
    u16x8* dst = (u16x8*)(Mout + (size_t)row * Q_ + lane * 16);
    dst[0] = *(u16x8*)&m16[0];
    dst[1] = *(u16x8*)&m16[8];
}

extern "C" void kernel_launch(void* const* d_in, const int* in_sizes, int n_in,
                              void* d_out, int out_size, void* d_ws, size_t ws_size,
                              hipStream_t stream) {
    const float* x  = (const float*)d_in[0];
    const float* W1 = (const float*)d_in[1];   // [2Q, Q]
    const float* W2 = (const float*)d_in[2];   // [Q, 2Q]
    const float* W3 = (const float*)d_in[3];   // [Q, Q]
    const float* Wc = (const float*)d_in[4];   // [E, Q]
    float* out = (float*)d_out;

    char* ws = (char*)d_ws;
    char* dob = (char*)d_out;
    // ---- ws map (fast path) ----
    us*    H1f  = (us*)ws;                          // pass-1 h1 fp16 [B,2Q] (128M)
    float* P1   = (float*)ws;                       // pass-2 L1 partials 4x32M (128M)
    us*    H1g0 = (us*)(ws + ((size_t)128 << 20));  // pass-2 h1 hi [CAPF,2Q] (16M)
    us*    H1g1 = (us*)(ws + ((size_t)144 << 20));  // pass-2 h1 lo (16M)
    us*    H2g0 = (us*)(ws + ((size_t)160 << 20));  // pass-2 h2 hi [CAPF,Q] (8M)
    us*    H2g1 = (us*)(ws + ((size_t)168 << 20));  // pass-2 h2 lo (8M)
    float* SCg  = (float*)(ws + ((size_t)176 << 20));// pass-2 scores [CAPF,Q] (16M)
    float4* PT  = (float4*)(ws + ((size_t)176 << 20));// argmax tiles [B][4] (2M, dead before SCg)
    us*    MASKB= (us*)(ws + ((size_t)192 << 20));  // mask bf16 [B,Q] (64M)
    int* KV     = (int*)(ws + ((size_t)256 << 20));
    int* FLAGS  = KV + B_;
    int* CNT    = FLAGS + B_;
    int* CNT2   = CNT + 1;
    int* FLAGS2 = CNT2 + 1;
    // ---- d_out map (scratch until final projection) ----
    us*    Xf   = (us*)dob;                         // x fp16 [B,Q] (64M)
    us*    H2f  = (us*)(dob + ((size_t)64 << 20));  // pass-1 h2 fp16 (64M)
    us*    Xg0  = (us*)dob;                         // gathered x hi (16M)
    us*    Xg1  = (us*)(dob + ((size_t)32 << 20));  // gathered x lo (16M)
    float* P23  = (float*)(dob + ((size_t)64 << 20));// pass-2 L2/L3 partials 4x16M (64M)
    float* H1F  = (float*)dob;                      // fp64-chain h1 [CAPF2,2Q] (8M)
    float* H2F  = (float*)(dob + ((size_t)8 << 20));
    float* SCF  = (float*)(dob + ((size_t)12 << 20));
    // ---- weight planes (fp16 first, overwritten by bf16 splits) ----
    char* WP = ws + ((size_t)256 << 20) + ((size_t)512 << 10);
    us* W1h = (us*)WP;                       us* W1f = (us*)WP;
    us* W1l = W1h + (size_t)2 * Q_ * Q_;
    us* W2h = W1l + (size_t)2 * Q_ * Q_;     us* W2f = W1l;   // overlaps (dead by then)
    us* W2l = W2h + (size_t)2 * Q_ * Q_;
    us* W3h = W2l + (size_t)2 * Q_ * Q_;     us* W3f = W2h;   // overlaps (dead by then)
    us* W3l = W3h + (size_t)Q_ * Q_;
    us* Wch = W3l + (size_t)Q_ * Q_;
    const size_t NEEDED = ((size_t)256 << 20) + ((size_t)512 << 10) + ((size_t)22 << 20);

    const size_t PS1 = (size_t)CAPF * 2 * Q_;   // partial stride (floats)
    const size_t PS2 = (size_t)CAPF * Q_;

    hipMemsetAsync(CNT, 0, 2 * sizeof(int), stream);
    dim3 blk(256);

    if (ws_size >= NEEDED) {
        // --- pass-1: fp16 single-pass selector (fused prep: 1 launch) ---
        const int ex  = B_ * Q_ / 8;
        const int ew1 = ex + 2 * Q_ * Q_ / 8;
        const int ew2 = ew1 + 2 * Q_ * Q_ / 8;
        const int ew3 = ew2 + Q_ * Q_ / 8;
        cvt4_h<<<dim3(2048), blk, 0, stream>>>(x, Xf, ex, W1, W1f, ew1,
                                               W2, W2f, ew2, W3, W3f, ew3);
        gemm4r<1, Q_,     2, true,  true ><<<dim3(1024), dim3(512), 0, stream>>>(
            Xf,  nullptr, W1f, nullptr, H1f, nullptr, 2 * Q_);
        gemm4r<1, 2 * Q_, 2, true,  true ><<<dim3(512),  dim3(512), 0, stream>>>(
            H1f, nullptr, W2f, nullptr, H2f, nullptr, Q_);
        // L3 with fused per-tile top-2 argmax epilogue (EMIT=3 -> PT table)
        gemm4r<1, Q_,     3, false, true ><<<dim3(512),  dim3(512), 0, stream>>>(
            H2f, nullptr, W3f, nullptr, PT,  nullptr, Q_);
        argmax_merge<<<dim3(B_ / 256), blk, 0, stream>>>(PT, Q_ >> 8, KV, FLAGS, CNT, 0.008f);
        // --- pass-2: bf16 3-pass split-K=4 on gathered flagged rows ---
        const int es1 = 2 * Q_ * Q_ / 8;
        const int es2 = es1 + 2 * Q_ * Q_ / 8;
        const int es3 = es2 + Q_ * Q_ / 8;
        split3_k<<<dim3(1024), blk, 0, stream>>>(W1, W1h, W1l, es1,
                                                 W2, W2h, W2l, es2,
                                                 W3, W3h, W3l, es3);
        cvt_plane_k<<<dim3(512), blk, 0, stream>>>(Wc, Wch, E_ * Q_ / 8);
        gather_split<<<dim3(2048), blk, 0, stream>>>(x, FLAGS, CNT, Xg0, Xg1);
        gemm_sp<3, 4><<<dim3((CAPF / 128) * (2 * Q_ / 128), 4), blk, 0, stream>>>(
            Xg0,  Xg1,  W1h, W1l, P1,  PS1, 2 * Q_, Q_, CNT);
        finalize_k<4, 1><<<dim3(2048), blk, 0, stream>>>(P1,  PS1, H1g0, H1g1, nullptr, CNT, 2 * Q_);
        gemm_sp<3, 4><<<dim3((CAPF / 128) * (Q_ / 128), 4), blk, 0, stream>>>(
            H1g0, H1g1, W2h, W2l, P23, PS2, Q_, 2 * Q_, CNT);
        finalize_k<4, 1><<<dim3(2048), blk, 0, stream>>>(P23, PS2, H2g0, H2g1, nullptr, CNT, Q_);
        gemm_sp<3, 4><<<dim3((CAPF / 128) * (Q_ / 128), 4), blk, 0, stream>>>(
            H2g0, H2g1, W3h, W3l, P23, PS2, Q_, Q_, CNT);
        finalize_k<4, 0><<<dim3(2048), blk, 0, stream>>>(P23, PS2, nullptr, nullptr, SCg, CNT, Q_);
        g_argmax_flag2<<<dim3(1024), blk, 0, stream>>>(SCg, FLAGS, CNT, KV, FLAGS2, CNT2);
        // --- pass-3: fp64 exact rescore of pass-2 near-ties ---
        rescore_gemm<Q_,     true,  true ><<<dim3(4096), blk, 0, stream>>>(x,   W1, H1F, FLAGS2, CNT2, 2 * Q_, CAPF2);
        rescore_gemm<2 * Q_, false, true ><<<dim3(2048), blk, 0, stream>>>(H1F, W2, H2F, FLAGS2, CNT2, Q_,     CAPF2);
        rescore_gemm<Q_,     false, false><<<dim3(2048), blk, 0, stream>>>(H2F, W3, SCF, FLAGS2, CNT2, Q_,     CAPF2);
        rescore_argmax<<<dim3(64), blk, 0, stream>>>(SCF, FLAGS2, CNT2, KV, CAPF2);
        // --- mask + projection ---
        topk_mask_radix<<<dim3(B_ / 4), blk, 0, stream>>>(x, KV, MASKB);
        gemm4r<1, Q_, 0, false, false><<<dim3(512), dim3(512), 0, stream>>>(
            MASKB, nullptr, Wch, nullptr, out, nullptr, E_);
    } else {
        // fallback: round-4 path (in-kernel split, fp32 weights)
        us*    H1_0 = (us*)ws;
        us*    H1_1 = (us*)(ws + ((size_t)128 << 20));
        float* SCo  = (float*)ws;
        us*    MB   = (us*)(ws + ((size_t)128 << 20));
        us* H2_0 = (us*)d_out;
        us* H2_1 = (us*)d_out + (size_t)B_ * Q_;
        float* H1Fo = (float*)ws;
        float* H2Fo = (float*)(ws + ((size_t)128 << 20));
        float* SCFo = (float*)(ws + ((size_t)192 << 20));
        gemm3p<3, true,  true,  true ><<<dim3(2 * Q_ / 128, B_ / 128), blk, 0, stream>>>(
            x, nullptr, W1, H1_0, H1_1, B_, 2 * Q_, Q_);
        gemm3p<3, false, true,  true ><<<dim3(Q_ / 128, B_ / 128), blk, 0, stream>>>(
            H1_0, H1_1, W2, H2_0, H2_1, B_, Q_, 2 * Q_);
        gemm3p<3, false, false, false><<<dim3(Q_ / 128, B_ / 128), blk, 0, stream>>>(
            H2_0, H2_1, W3, SCo, nullptr, B_, Q_, Q_);
        row_argmax_flag<<<dim3(B_ / 4), blk, 0, stream>>>(SCo, KV, FLAGS, CNT, 1e-3f);
        rescore_gemm<Q_,     true,  true ><<<dim3(4096), blk, 0, stream>>>(x,    W1, H1Fo, FLAGS, CNT, 2 * Q_, CAPF);
        rescore_gemm<2 * Q_, false, true ><<<dim3(2048), blk, 0, stream>>>(H1Fo, W2, H2Fo, FLAGS, CNT, Q_,     CAPF);
        rescore_gemm<Q_,     false, false><<<dim3(2048), blk, 0, stream>>>(H2Fo, W3, SCFo, FLAGS, CNT, Q_,     CAPF);
        rescore_argmax<<<dim3(64), blk, 0, stream>>>(SCFo, FLAGS, CNT, KV, CAPF);
        topk_mask_radix<<<dim3(B_ / 4), blk, 0, stream>>>(x, KV, MB);
        gemm3p<1, false, false, false><<<dim3(E_ / 128, B_ / 128), blk, 0, stream>>>(
            MB, nullptr, Wc, out, nullptr, B_, E_, Q_);
    }
}